// Round 2
// baseline (354.763 us; speedup 1.0000x reference)
//
#include <hip/hip_runtime.h>
#include <hip/hip_bf16.h>
#include <stdint.h>

// Problem constants
#define B_  4
#define T_  2048
#define C_  1024
#define H_  16
#define D_  64
#define BT  (B_*T_)     // 8192
#define KDIM 1024

typedef __attribute__((ext_vector_type(8))) short bf16x8;
typedef __attribute__((ext_vector_type(4))) float f32x4;

__device__ __forceinline__ unsigned short f2bf(float f) {
  union { float f; unsigned u; } v; v.f = f;
  unsigned r = v.u + 0x7FFFu + ((v.u >> 16) & 1u);   // RNE
  return (unsigned short)(r >> 16);
}

// async global->LDS, 16B per lane. dest must be wave-uniform base + lane*16 (linear).
__device__ __forceinline__ void gld_lds16(const void* g, void* l) {
  __builtin_amdgcn_global_load_lds(
      (__attribute__((address_space(1))) unsigned int*)(uintptr_t)g,
      (__attribute__((address_space(3))) unsigned int*)(unsigned)(uintptr_t)l,
      16, 0, 0);
}

// ---------------------------------------------------------------- prep kernels
__global__ __launch_bounds__(256) void k_convert(
    const float* __restrict__ x,  const float* __restrict__ wq,
    const float* __restrict__ wk, const float* __restrict__ wv,
    const float* __restrict__ wp,
    unsigned short* __restrict__ xb, unsigned short* __restrict__ wcat,
    unsigned short* __restrict__ wpb)
{
  const int NX = BT*C_/4;       // 2097152 float4s of x
  const int NW = C_*C_/4;       // 262144 per W
  const int TOT = NX + 4*NW;
  for (int i = blockIdx.x*blockDim.x + threadIdx.x; i < TOT; i += gridDim.x*blockDim.x) {
    const float4* src; unsigned short* dst; int idx;
    if (i < NX)                { src = (const float4*)x;  dst = xb;            idx = i; }
    else {
      int j = i - NX;
      if (j < NW)              { src = (const float4*)wq; dst = wcat;          idx = j; }
      else if (j < 2*NW)       { src = (const float4*)wk; dst = wcat + C_*C_;  idx = j - NW; }
      else if (j < 3*NW)       { src = (const float4*)wv; dst = wcat + 2*C_*C_;idx = j - 2*NW; }
      else                     { src = (const float4*)wp; dst = wpb;           idx = j - 3*NW; }
    }
    float4 v = src[idx];
    ushort4 o; o.x = f2bf(v.x); o.y = f2bf(v.y); o.z = f2bf(v.z); o.w = f2bf(v.w);
    *(ushort4*)(dst + (size_t)idx*4) = o;
  }
}

// Reference quirk: emb = concat([freqs,freqs]) -> angle for element j is t*invf[j%32],
// while rotate_half is interleaved (partner = j^1).
__global__ __launch_bounds__(256) void k_rope_tab(
    const int* __restrict__ start_pos, float* __restrict__ cosT, float* __restrict__ sinT)
{
  int i = blockIdx.x*blockDim.x + threadIdx.x;   // [0, T_*64)
  if (i >= T_*D_) return;
  int t = i >> 6, j = i & 63;
  // invf = 10000^(-(j%32)/32) = 2^(-log2(1e4)*(j%32)/32)
  float inv = exp2f(-(float)(j & 31) * (13.287712379549449f / 32.0f));
  float ang = (float)(t + start_pos[0]) * inv;
  cosT[i] = cosf(ang);
  sinT[i] = sinf(ang);
}

// ---------------------------------------------------------------- GEMM (NT, bf16)
// C[m,n] = sum_k A[m,k]*Bw[n,k].  128x128 tile, BK=64, 4 waves (2x2), mfma 16x16x32.
// LDS XOR-swizzle (T2): physical byte P in a [rows][128B] tile stores logical
// L = P ^ ((row&7)<<4); staging source is inverse-permuted, dest stays linear (rule 21).
// EPI 0: fused RoPE -> qb/kb (B,H,T,D) bf16 (q pre-scaled by 1/8), v transposed
//        -> vt (B,H,D,T) bf16 via 8B ushort4 stores (4 consecutive t per lane).
// EPI 1: plain f32 store to outF.
template<int EPI>
__global__ __launch_bounds__(256) void k_gemm(
    const unsigned short* __restrict__ A, const unsigned short* __restrict__ Bw,
    unsigned short* __restrict__ qb, unsigned short* __restrict__ kb,
    unsigned short* __restrict__ vt,
    const float* __restrict__ cosT, const float* __restrict__ sinT,
    float* __restrict__ outF)
{
  __shared__ __attribute__((aligned(16))) char smem[32768];  // A:16K B:16K
  const int tid = threadIdx.x, l = tid & 63, w = tid >> 6;
  const int g = l >> 4, c = l & 15;
  const int m0 = blockIdx.x * 128, n0 = blockIdx.y * 128;
  const int wr = w >> 1, wc = w & 1;

  // staging descriptors (4 x 16B per thread per tile)
  const char* srcA[4]; const char* srcB[4]; int dstP[4];
#pragma unroll
  for (int j = 0; j < 4; ++j) {
    int P = w*4096 + j*1024 + l*16;
    int row = P >> 7;
    int Lb = P ^ ((row & 7) << 4);
    int col = (Lb & 127) >> 1;
    dstP[j] = P;
    srcA[j] = (const char*)A  + ((size_t)(m0 + row) * KDIM + col) * 2;
    srcB[j] = (const char*)Bw + ((size_t)(n0 + row) * KDIM + col) * 2;
  }

  f32x4 acc[4][4];
#pragma unroll
  for (int i = 0; i < 4; ++i)
#pragma unroll
    for (int j = 0; j < 4; ++j) acc[i][j] = (f32x4){0.f,0.f,0.f,0.f};

  for (int kt = 0; kt < KDIM; kt += 64) {
#pragma unroll
    for (int j = 0; j < 4; ++j) {
      gld_lds16(srcA[j] + kt*2, smem + dstP[j]);
      gld_lds16(srcB[j] + kt*2, smem + 16384 + dstP[j]);
    }
    __syncthreads();
#pragma unroll
    for (int kk = 0; kk < 2; ++kk) {
      bf16x8 af[4], bw4[4];
#pragma unroll
      for (int mi = 0; mi < 4; ++mi) {
        int row = wr*64 + mi*16 + c;
        int Lb = row*128 + (kk*32 + g*8)*2;
        af[mi] = *(const bf16x8*)(smem + (Lb ^ ((row & 7) << 4)));
      }
#pragma unroll
      for (int ni = 0; ni < 4; ++ni) {
        int row = wc*64 + ni*16 + c;
        int Lb = row*128 + (kk*32 + g*8)*2;
        bw4[ni] = *(const bf16x8*)(smem + 16384 + (Lb ^ ((row & 7) << 4)));
      }
#pragma unroll
      for (int mi = 0; mi < 4; ++mi)
#pragma unroll
        for (int ni = 0; ni < 4; ++ni)
          acc[mi][ni] = __builtin_amdgcn_mfma_f32_16x16x32_bf16(af[mi], bw4[ni], acc[mi][ni], 0, 0, 0);
    }
    __syncthreads();
  }

  // epilogue; C layout: col = lane&15, row = (lane>>4)*4 + r
#pragma unroll
  for (int mi = 0; mi < 4; ++mi) {
#pragma unroll
    for (int ni = 0; ni < 4; ++ni) {
      const int mrow0 = m0 + wr*64 + mi*16 + g*4;
      const int ncol  = n0 + wc*64 + ni*16 + c;
      if (EPI == 1) {
#pragma unroll
        for (int r = 0; r < 4; ++r)
          outF[(size_t)(mrow0 + r) * 1024 + ncol] = acc[mi][ni][r];
      } else {
        const int which = ncol >> 10;          // 0=q 1=k 2=v (wave-uniform)
        const int d = ncol & 1023, h = d >> 6, dd = d & 63;
        const int b = mrow0 >> 11, t0 = mrow0 & 2047;
        if (which == 2) {
          // v transposed: vt[(b,h,dd), t0..t0+3] as one 8B store
          ushort4 o;
          o.x = f2bf(acc[mi][ni][0]); o.y = f2bf(acc[mi][ni][1]);
          o.z = f2bf(acc[mi][ni][2]); o.w = f2bf(acc[mi][ni][3]);
          *(ushort4*)(vt + ((size_t)((b*H_ + h)*D_ + dd))*T_ + t0) = o;
        } else {
#pragma unroll
          for (int r = 0; r < 4; ++r) {
            float val = acc[mi][ni][r];
            float partner = __shfl_xor(val, 1);          // value at dd^1 (lane^1)
            float rot = (dd & 1) ? partner : -partner;   // interleaved rotate_half
            float cv = cosT[(t0 + r)*64 + dd], sv = sinT[(t0 + r)*64 + dd];
            float o = val*cv + rot*sv;
            size_t oidx = (((size_t)(b*H_ + h))*T_ + (t0 + r))*D_ + dd;
            if (which == 0) qb[oidx] = f2bf(o * 0.125f); // fold 1/sqrt(64)
            else            kb[oidx] = f2bf(o);
          }
        }
      }
    }
  }
}

// ---------------------------------------------------------------- flash attention
// One block = one (bh, 128-row q tile). 4 waves x 32 rows. KV tile = 64.
// K tile:  [64 kv][64 d] bf16, XOR-swizzled rows of 128B.
// Vt tile: [64 d][64 kv] bf16 (from pre-transposed vt), XOR-swizzled — PV's
//          B-operand becomes a plain contiguous swizzled read (same pattern as K).
// P: per-wave swizzled LDS roundtrip C-layout -> A-layout.
__global__ __launch_bounds__(256) void k_attn(
    const unsigned short* __restrict__ qb, const unsigned short* __restrict__ kb,
    const unsigned short* __restrict__ vt, unsigned short* __restrict__ yb)
{
  __shared__ __attribute__((aligned(16))) char smem[32768]; // K:8K Vt:8K P:16K
  const int tid = threadIdx.x, l = tid & 63, w = tid >> 6;
  const int g = l >> 4, c = l & 15;
  const int bh = blockIdx.y;
  const int qt = (int)gridDim.x - 1 - (int)blockIdx.x;  // heavy tiles first
  const int q0 = qt * 128;
  const size_t bhO = (size_t)bh * T_ * D_;   // element offset (same for kb and vt)

  // Q fragments in registers (q already scaled by 1/8)
  bf16x8 aq[2][2];
#pragma unroll
  for (int mi = 0; mi < 2; ++mi)
#pragma unroll
    for (int kc = 0; kc < 2; ++kc) {
      int row = q0 + w*32 + mi*16 + c;
      aq[mi][kc] = *(const bf16x8*)(qb + bhO + (size_t)row*D_ + kc*32 + g*8);
    }

  f32x4 po[2][4];
  float mrun[2][4], lrun[2][4];
#pragma unroll
  for (int mi = 0; mi < 2; ++mi) {
#pragma unroll
    for (int ni = 0; ni < 4; ++ni) po[mi][ni] = (f32x4){0.f,0.f,0.f,0.f};
#pragma unroll
    for (int r = 0; r < 4; ++r) { mrun[mi][r] = -1e30f; lrun[mi][r] = 0.f; }
  }

  // staging descriptors (2 x 16B per thread for K, 2 for Vt)
  const char* srcK[2]; const char* srcV[2]; int dstP2[2];
#pragma unroll
  for (int j = 0; j < 2; ++j) {
    int P = w*2048 + j*1024 + l*16;
    int row = P >> 7;                       // K: kv index   Vt: d index
    int Lb = P ^ ((row & 7) << 4);
    int col = (Lb & 127) >> 1;              // K: d offset   Vt: kv offset
    dstP2[j] = P;
    srcK[j] = (const char*)(kb + bhO) + ((size_t)row*D_ + col)*2;   // + kv0*128B/iter
    srcV[j] = (const char*)(vt + bhO) + ((size_t)row*T_ + col)*2;   // + kv0*2B/iter
  }

  const int nkt = (q0 + 128) >> 6;
  for (int it = 0; it < nkt; ++it) {
    const int kv0 = it * 64;
#pragma unroll
    for (int j = 0; j < 2; ++j) {
      gld_lds16(srcK[j] + (size_t)kv0*128, smem + dstP2[j]);
      gld_lds16(srcV[j] + (size_t)kv0*2,   smem + 8192 + dstP2[j]);
    }
    __syncthreads();

    // ---- S = Q K^T  (32 rows x 64 kv per wave)
    f32x4 s[2][4];
#pragma unroll
    for (int mi = 0; mi < 2; ++mi)
#pragma unroll
      for (int ni = 0; ni < 4; ++ni) s[mi][ni] = (f32x4){0.f,0.f,0.f,0.f};
#pragma unroll
    for (int kk = 0; kk < 2; ++kk) {
      bf16x8 bk[4];
#pragma unroll
      for (int ni = 0; ni < 4; ++ni) {
        int kn = ni*16 + c;
        int Lb = kn*128 + (kk*32 + g*8)*2;
        bk[ni] = *(const bf16x8*)(smem + (Lb ^ ((kn & 7) << 4)));
      }
#pragma unroll
      for (int mi = 0; mi < 2; ++mi)
#pragma unroll
        for (int ni = 0; ni < 4; ++ni)
          s[mi][ni] = __builtin_amdgcn_mfma_f32_16x16x32_bf16(aq[mi][kk], bk[ni], s[mi][ni], 0, 0, 0);
    }

    // ---- causal mask
#pragma unroll
    for (int mi = 0; mi < 2; ++mi) {
      int qrow = q0 + w*32 + mi*16 + g*4;
#pragma unroll
      for (int ni = 0; ni < 4; ++ni) {
        int kcol = kv0 + ni*16 + c;
#pragma unroll
        for (int r = 0; r < 4; ++r)
          if (kcol > qrow + r) s[mi][ni][r] = -1e30f;
      }
    }

    // ---- online softmax (wave-parallel; 16-lane col groups)
#pragma unroll
    for (int mi = 0; mi < 2; ++mi) {
#pragma unroll
      for (int r = 0; r < 4; ++r) {
        float rowm = fmaxf(fmaxf(s[mi][0][r], s[mi][1][r]), fmaxf(s[mi][2][r], s[mi][3][r]));
        rowm = fmaxf(rowm, __shfl_xor(rowm, 1));
        rowm = fmaxf(rowm, __shfl_xor(rowm, 2));
        rowm = fmaxf(rowm, __shfl_xor(rowm, 4));
        rowm = fmaxf(rowm, __shfl_xor(rowm, 8));
        float mold = mrun[mi][r];
        float mnew = fmaxf(mold, rowm);
        float alpha = __expf(mold - mnew);
        mrun[mi][r] = mnew;
        float rs = 0.f;
#pragma unroll
        for (int ni = 0; ni < 4; ++ni) {
          float p = __expf(s[mi][ni][r] - mnew);
          s[mi][ni][r] = p;
          rs += p;
        }
        rs += __shfl_xor(rs, 1);
        rs += __shfl_xor(rs, 2);
        rs += __shfl_xor(rs, 4);
        rs += __shfl_xor(rs, 8);
        lrun[mi][r] = lrun[mi][r]*alpha + rs;
#pragma unroll
        for (int ni = 0; ni < 4; ++ni) po[mi][ni][r] *= alpha;
      }
    }

    // ---- P -> LDS (per-wave region, swizzled), C-layout -> A-layout
    const int pbase = 16384 + w*4096;
#pragma unroll
    for (int mi = 0; mi < 2; ++mi)
#pragma unroll
      for (int ni = 0; ni < 4; ++ni)
#pragma unroll
        for (int r = 0; r < 4; ++r) {
          int pr = mi*16 + g*4 + r;
          int pc = ni*16 + c;
          int Lb = pr*128 + pc*2;
          *(unsigned short*)(smem + pbase + (Lb ^ ((pr & 7) << 4))) = f2bf(s[mi][ni][r]);
        }

    // ---- PV: O += P * V   (B-operand from Vt tile, plain swizzled reads)
#pragma unroll
    for (int kk = 0; kk < 2; ++kk) {
      bf16x8 pa[2];
#pragma unroll
      for (int mi = 0; mi < 2; ++mi) {
        int pr = mi*16 + c;
        int Lb = pr*128 + (kk*32 + g*8)*2;
        pa[mi] = *(const bf16x8*)(smem + pbase + (Lb ^ ((pr & 7) << 4)));
      }
      bf16x8 bv[4];
#pragma unroll
      for (int ni = 0; ni < 4; ++ni) {
        int vr = ni*16 + c;                      // d index
        int Lb = vr*128 + (kk*32 + g*8)*2;       // kv offset contiguous
        bv[ni] = *(const bf16x8*)(smem + 8192 + (Lb ^ ((vr & 7) << 4)));
      }
#pragma unroll
      for (int mi = 0; mi < 2; ++mi)
#pragma unroll
        for (int ni = 0; ni < 4; ++ni)
          po[mi][ni] = __builtin_amdgcn_mfma_f32_16x16x32_bf16(pa[mi], bv[ni], po[mi][ni], 0, 0, 0);
    }
    __syncthreads();   // protect K/Vt/P tiles before next stage
  }

  // ---- normalize + store y as (B*T, C) bf16
  const int b = bh >> 4, h = bh & 15;
#pragma unroll
  for (int mi = 0; mi < 2; ++mi)
#pragma unroll
    for (int r = 0; r < 4; ++r) {
      float inv = 1.f / lrun[mi][r];
      int t = q0 + w*32 + mi*16 + g*4 + r;
#pragma unroll
      for (int ni = 0; ni < 4; ++ni) {
        int dd = ni*16 + c;
        yb[((size_t)b*T_ + t)*C_ + h*64 + dd] = f2bf(po[mi][ni][r] * inv);
      }
    }
}

// ---------------------------------------------------------------- launcher
extern "C" void kernel_launch(void* const* d_in, const int* in_sizes, int n_in,
                              void* d_out, int out_size, void* d_ws, size_t ws_size,
                              hipStream_t stream)
{
  const float* x  = (const float*)d_in[0];
  const float* Wq = (const float*)d_in[1];
  const float* Wk = (const float*)d_in[2];
  const float* Wv = (const float*)d_in[3];
  const float* Wp = (const float*)d_in[4];
  const int*   sp = (const int*)d_in[5];
  float* out = (float*)d_out;

  char* ws = (char*)d_ws;
  unsigned short* xb   = (unsigned short*)(ws);                  // 16 MB
  unsigned short* wcat = (unsigned short*)(ws + 16777216);       // 6 MB [Wq;Wk;Wv]
  unsigned short* wpb  = (unsigned short*)(ws + 23068672);       // 2 MB
  unsigned short* qb   = (unsigned short*)(ws + 25165824);       // 16 MB (B,H,T,D)
  unsigned short* kb   = (unsigned short*)(ws + 41943040);       // 16 MB (B,H,T,D)
  unsigned short* vt   = (unsigned short*)(ws + 58720256);       // 16 MB (B,H,D,T)
  unsigned short* yb   = (unsigned short*)(ws + 75497472);       // 16 MB (B*T, C)
  float* cosT = (float*)(ws + 92274688);                         // 512 KB
  float* sinT = (float*)(ws + 92798976);                         // 512 KB

  k_convert<<<dim3(2048), dim3(256), 0, stream>>>(x, Wq, Wk, Wv, Wp, xb, wcat, wpb);
  k_rope_tab<<<dim3(512), dim3(256), 0, stream>>>(sp, cosT, sinT);
  k_gemm<0><<<dim3(64, 24), dim3(256), 0, stream>>>(xb, wcat, qb, kb, vt, cosT, sinT, nullptr);
  k_attn<<<dim3(16, 64), dim3(256), 0, stream>>>(qb, kb, vt, yb);
  k_gemm<1><<<dim3(64, 8), dim3(256), 0, stream>>>(yb, wpb, nullptr, nullptr, nullptr, nullptr, nullptr, out);
}

// Round 4
// 243.619 us; speedup vs baseline: 1.4562x; 1.4562x over previous
//
#include <hip/hip_runtime.h>
#include <hip/hip_bf16.h>
#include <stdint.h>

// Problem constants
#define B_  4
#define T_  2048
#define C_  1024
#define H_  16
#define D_  64
#define BT  (B_*T_)     // 8192
#define KDIM 1024

typedef __attribute__((ext_vector_type(8))) short bf16x8;
typedef __attribute__((ext_vector_type(4))) float f32x4;

__device__ __forceinline__ unsigned short f2bf(float f) {
  union { float f; unsigned u; } v; v.f = f;
  unsigned r = v.u + 0x7FFFu + ((v.u >> 16) & 1u);   // RNE
  return (unsigned short)(r >> 16);
}

// async global->LDS, 16B per lane. dest must be wave-uniform base + lane*16 (linear).
__device__ __forceinline__ void gld_lds16(const void* g, void* l) {
  __builtin_amdgcn_global_load_lds(
      (__attribute__((address_space(1))) unsigned int*)(uintptr_t)g,
      (__attribute__((address_space(3))) unsigned int*)(unsigned)(uintptr_t)l,
      16, 0, 0);
}

// ---------------------------------------------------------------- prep kernels
__global__ __launch_bounds__(256) void k_convert(
    const float* __restrict__ x,  const float* __restrict__ wq,
    const float* __restrict__ wk, const float* __restrict__ wv,
    const float* __restrict__ wp,
    unsigned short* __restrict__ xb, unsigned short* __restrict__ wcat,
    unsigned short* __restrict__ wpb)
{
  const int NX = BT*C_/4;       // 2097152 float4s of x
  const int NW = C_*C_/4;       // 262144 per W
  const int TOT = NX + 4*NW;
  for (int i = blockIdx.x*blockDim.x + threadIdx.x; i < TOT; i += gridDim.x*blockDim.x) {
    const float4* src; unsigned short* dst; int idx;
    if (i < NX)                { src = (const float4*)x;  dst = xb;            idx = i; }
    else {
      int j = i - NX;
      if (j < NW)              { src = (const float4*)wq; dst = wcat;          idx = j; }
      else if (j < 2*NW)       { src = (const float4*)wk; dst = wcat + C_*C_;  idx = j - NW; }
      else if (j < 3*NW)       { src = (const float4*)wv; dst = wcat + 2*C_*C_;idx = j - 2*NW; }
      else                     { src = (const float4*)wp; dst = wpb;           idx = j - 3*NW; }
    }
    float4 v = src[idx];
    ushort4 o; o.x = f2bf(v.x); o.y = f2bf(v.y); o.z = f2bf(v.z); o.w = f2bf(v.w);
    *(ushort4*)(dst + (size_t)idx*4) = o;
  }
}

// Reference quirk: emb = concat([freqs,freqs]) -> angle for element j is t*invf[j%32],
// while rotate_half is interleaved (partner = j^1).
__global__ __launch_bounds__(256) void k_rope_tab(
    const int* __restrict__ start_pos, float* __restrict__ cosT, float* __restrict__ sinT)
{
  int i = blockIdx.x*blockDim.x + threadIdx.x;   // [0, T_*64)
  if (i >= T_*D_) return;
  int t = i >> 6, j = i & 63;
  float inv = exp2f(-(float)(j & 31) * (13.287712379549449f / 32.0f));
  float ang = (float)(t + start_pos[0]) * inv;
  cosT[i] = cosf(ang);
  sinT[i] = sinf(ang);
}

// ---------------------------------------------------------------- GEMM (NT, bf16)
// (unchanged from R2 passing kernel)
template<int EPI>
__global__ __launch_bounds__(256) void k_gemm(
    const unsigned short* __restrict__ A, const unsigned short* __restrict__ Bw,
    unsigned short* __restrict__ qb, unsigned short* __restrict__ kb,
    unsigned short* __restrict__ vt,
    const float* __restrict__ cosT, const float* __restrict__ sinT,
    float* __restrict__ outF)
{
  __shared__ __attribute__((aligned(16))) char smem[32768];  // A:16K B:16K
  const int tid = threadIdx.x, l = tid & 63, w = tid >> 6;
  const int g = l >> 4, c = l & 15;
  const int m0 = blockIdx.x * 128, n0 = blockIdx.y * 128;
  const int wr = w >> 1, wc = w & 1;

  const char* srcA[4]; const char* srcB[4]; int dstP[4];
#pragma unroll
  for (int j = 0; j < 4; ++j) {
    int P = w*4096 + j*1024 + l*16;
    int row = P >> 7;
    int Lb = P ^ ((row & 7) << 4);
    int col = (Lb & 127) >> 1;
    dstP[j] = P;
    srcA[j] = (const char*)A  + ((size_t)(m0 + row) * KDIM + col) * 2;
    srcB[j] = (const char*)Bw + ((size_t)(n0 + row) * KDIM + col) * 2;
  }

  f32x4 acc[4][4];
#pragma unroll
  for (int i = 0; i < 4; ++i)
#pragma unroll
    for (int j = 0; j < 4; ++j) acc[i][j] = (f32x4){0.f,0.f,0.f,0.f};

  for (int kt = 0; kt < KDIM; kt += 64) {
#pragma unroll
    for (int j = 0; j < 4; ++j) {
      gld_lds16(srcA[j] + kt*2, smem + dstP[j]);
      gld_lds16(srcB[j] + kt*2, smem + 16384 + dstP[j]);
    }
    __syncthreads();
#pragma unroll
    for (int kk = 0; kk < 2; ++kk) {
      bf16x8 af[4], bw4[4];
#pragma unroll
      for (int mi = 0; mi < 4; ++mi) {
        int row = wr*64 + mi*16 + c;
        int Lb = row*128 + (kk*32 + g*8)*2;
        af[mi] = *(const bf16x8*)(smem + (Lb ^ ((row & 7) << 4)));
      }
#pragma unroll
      for (int ni = 0; ni < 4; ++ni) {
        int row = wc*64 + ni*16 + c;
        int Lb = row*128 + (kk*32 + g*8)*2;
        bw4[ni] = *(const bf16x8*)(smem + 16384 + (Lb ^ ((row & 7) << 4)));
      }
#pragma unroll
      for (int mi = 0; mi < 4; ++mi)
#pragma unroll
        for (int ni = 0; ni < 4; ++ni)
          acc[mi][ni] = __builtin_amdgcn_mfma_f32_16x16x32_bf16(af[mi], bw4[ni], acc[mi][ni], 0, 0, 0);
    }
    __syncthreads();
  }

  // epilogue; C layout: col = lane&15, row = (lane>>4)*4 + r
#pragma unroll
  for (int mi = 0; mi < 4; ++mi) {
#pragma unroll
    for (int ni = 0; ni < 4; ++ni) {
      const int mrow0 = m0 + wr*64 + mi*16 + g*4;
      const int ncol  = n0 + wc*64 + ni*16 + c;
      if (EPI == 1) {
#pragma unroll
        for (int r = 0; r < 4; ++r)
          outF[(size_t)(mrow0 + r) * 1024 + ncol] = acc[mi][ni][r];
      } else {
        const int which = ncol >> 10;          // 0=q 1=k 2=v (wave-uniform)
        const int d = ncol & 1023, h = d >> 6, dd = d & 63;
        const int b = mrow0 >> 11, t0 = mrow0 & 2047;
        if (which == 2) {
          ushort4 o;
          o.x = f2bf(acc[mi][ni][0]); o.y = f2bf(acc[mi][ni][1]);
          o.z = f2bf(acc[mi][ni][2]); o.w = f2bf(acc[mi][ni][3]);
          *(ushort4*)(vt + ((size_t)((b*H_ + h)*D_ + dd))*T_ + t0) = o;
        } else {
#pragma unroll
          for (int r = 0; r < 4; ++r) {
            float val = acc[mi][ni][r];
            float partner = __shfl_xor(val, 1);          // value at dd^1 (lane^1)
            float rot = (dd & 1) ? partner : -partner;   // interleaved rotate_half
            float cv = cosT[(t0 + r)*64 + dd], sv = sinT[(t0 + r)*64 + dd];
            float o = val*cv + rot*sv;
            size_t oidx = (((size_t)(b*H_ + h))*T_ + (t0 + r))*D_ + dd;
            if (which == 0) qb[oidx] = f2bf(o * 0.125f); // fold 1/sqrt(64)
            else            kb[oidx] = f2bf(o);
          }
        }
      }
    }
  }
}

// ---------------------------------------------------------------- flash attention
// Transposed-S structure: S^T = mfma(K, Q) so each lane owns whole q-rows
// (q = lane&15): softmax reduce is in-lane + 2 shfl. P^T packed via
// v_cvt_pk_bf16_f32 (r-pairs are adjacent kv) -> 16 ds_write_b32; PV computed
// as O^T = mfma(Vt, P^T) (identical LDS read patterns to R2's verified reads).
// K/Vt tiles double-buffered; fully-masked tiles skip compute (barriers kept).
// MASK CONDITION (R3 bug fixed): wave q rows [q0w,q0w+32), kv tile [kv0,kv0+64)
// -> mask needed iff kv0+64 > q0w (NOT kv0+32 > q0w).
__global__ __launch_bounds__(256) void k_attn(
    const unsigned short* __restrict__ qb, const unsigned short* __restrict__ kb,
    const unsigned short* __restrict__ vt, unsigned short* __restrict__ yb)
{
  __shared__ __attribute__((aligned(16))) char smem[49152]; // 2x(K:8K V:8K) + P:16K
  const int tid = threadIdx.x, l = tid & 63, w = tid >> 6;
  const int g = l >> 4, c = l & 15;
  const int bh = blockIdx.y;
  const int qt = (int)gridDim.x - 1 - (int)blockIdx.x;  // heavy tiles first
  const int q0 = qt * 128;
  const int q0w = q0 + w*32;                            // this wave's q rows
  const size_t bhO = (size_t)bh * T_ * D_;
  const int pbase = 32768 + w*4096;

  // Q fragments in registers (q already scaled by 1/8)
  bf16x8 aq[2][2];
#pragma unroll
  for (int mi = 0; mi < 2; ++mi)
#pragma unroll
    for (int kc = 0; kc < 2; ++kc) {
      int row = q0w + mi*16 + c;
      aq[mi][kc] = *(const bf16x8*)(qb + bhO + (size_t)row*D_ + kc*32 + g*8);
    }

  f32x4 po[4][2];                 // O^T: [nd][mi], lane: d=nd*16+g*4+r, q=mi*16+c
  float mrun[2], lrun[2];
#pragma unroll
  for (int nd = 0; nd < 4; ++nd)
#pragma unroll
    for (int mi = 0; mi < 2; ++mi) po[nd][mi] = (f32x4){0.f,0.f,0.f,0.f};
  mrun[0] = mrun[1] = -1e30f; lrun[0] = lrun[1] = 0.f;

  // staging descriptors (2 x 16B per thread for K, 2 for Vt)
  const char* srcK[2]; const char* srcV[2]; int dstP2[2];
#pragma unroll
  for (int j = 0; j < 2; ++j) {
    int P = w*2048 + j*1024 + l*16;
    int row = P >> 7;                       // K: kv index   Vt: d index
    int Lb = P ^ ((row & 7) << 4);
    int col = (Lb & 127) >> 1;              // K: d offset   Vt: kv offset
    dstP2[j] = P;
    srcK[j] = (const char*)(kb + bhO) + ((size_t)row*D_ + col)*2;   // + kv0*128B/iter
    srcV[j] = (const char*)(vt + bhO) + ((size_t)row*T_ + col)*2;   // + kv0*2B/iter
  }

  const int nkt = (q0 + 128) >> 6;

  // prologue: stage tile 0 into buffer 0
#pragma unroll
  for (int j = 0; j < 2; ++j) {
    gld_lds16(srcK[j], smem + dstP2[j]);
    gld_lds16(srcV[j], smem + 8192 + dstP2[j]);
  }
  __syncthreads();

  for (int it = 0; it < nkt; ++it) {
    const int kv0 = it * 64;
    const int cur = (it & 1) * 16384;
    // stage next tile into the other buffer (hidden under compute)
    if (it + 1 < nkt) {
      const int nxt = 16384 - cur;
      const size_t ko = (size_t)(kv0 + 64) * 128;
      const size_t vo = (size_t)(kv0 + 64) * 2;
#pragma unroll
      for (int j = 0; j < 2; ++j) {
        gld_lds16(srcK[j] + ko, smem + nxt + dstP2[j]);
        gld_lds16(srcV[j] + vo, smem + nxt + 8192 + dstP2[j]);
      }
    }

    if (kv0 < q0w + 32) {          // tile has at least one unmasked element
      // ---- S^T = K Q^T  (64 kv x 32 q per wave)
      f32x4 st[4][2];
#pragma unroll
      for (int ni = 0; ni < 4; ++ni)
#pragma unroll
        for (int mi = 0; mi < 2; ++mi) st[ni][mi] = (f32x4){0.f,0.f,0.f,0.f};
      __builtin_amdgcn_s_setprio(1);
#pragma unroll
      for (int kk = 0; kk < 2; ++kk) {
        bf16x8 bk[4];
#pragma unroll
        for (int ni = 0; ni < 4; ++ni) {
          int kn = ni*16 + c;
          int Lb = kn*128 + (kk*32 + g*8)*2;
          bk[ni] = *(const bf16x8*)(smem + cur + (Lb ^ ((kn & 7) << 4)));
        }
#pragma unroll
        for (int ni = 0; ni < 4; ++ni)
#pragma unroll
          for (int mi = 0; mi < 2; ++mi)
            st[ni][mi] = __builtin_amdgcn_mfma_f32_16x16x32_bf16(bk[ni], aq[mi][kk], st[ni][mi], 0, 0, 0);
      }
      __builtin_amdgcn_s_setprio(0);

      // ---- causal mask (partial tiles only; wave-uniform branch)
      if (kv0 + 64 > q0w) {
#pragma unroll
        for (int ni = 0; ni < 4; ++ni)
#pragma unroll
          for (int r = 0; r < 4; ++r) {
            int kvv = kv0 + ni*16 + g*4 + r;
#pragma unroll
            for (int mi = 0; mi < 2; ++mi) {
              int qq = q0w + mi*16 + c;
              if (kvv > qq) st[ni][mi][r] = -1e30f;
            }
          }
      }

      // ---- online softmax: in-lane over 16 values + 2 shfl across g
#pragma unroll
      for (int mi = 0; mi < 2; ++mi) {
        float mt = -1e30f;
#pragma unroll
        for (int ni = 0; ni < 4; ++ni)
#pragma unroll
          for (int r = 0; r < 4; ++r) mt = fmaxf(mt, st[ni][mi][r]);
        mt = fmaxf(mt, __shfl_xor(mt, 16));
        mt = fmaxf(mt, __shfl_xor(mt, 32));
        float mold = mrun[mi];
        float mnew = fmaxf(mold, mt);
        float alpha = __expf(mold - mnew);
        mrun[mi] = mnew;
        float rs = 0.f;
#pragma unroll
        for (int ni = 0; ni < 4; ++ni)
#pragma unroll
          for (int r = 0; r < 4; ++r) {
            float p = __expf(st[ni][mi][r] - mnew);
            st[ni][mi][r] = p;
            rs += p;
          }
        rs += __shfl_xor(rs, 16);
        rs += __shfl_xor(rs, 32);
        lrun[mi] = lrun[mi]*alpha + rs;
#pragma unroll
        for (int nd = 0; nd < 4; ++nd)
#pragma unroll
          for (int r = 0; r < 4; ++r) po[nd][mi][r] *= alpha;
      }

      // ---- P^T -> LDS [q_local][kv_local] (packed pairs, swizzled, wave-private)
#pragma unroll
      for (int mi = 0; mi < 2; ++mi) {
        const int row = mi*16 + c;
        const int sw = (row & 7) << 4;
        const int rb = pbase + row*128;
#pragma unroll
        for (int ni = 0; ni < 4; ++ni) {
          unsigned u0, u1;
          asm("v_cvt_pk_bf16_f32 %0, %1, %2" : "=v"(u0) : "v"(st[ni][mi][0]), "v"(st[ni][mi][1]));
          asm("v_cvt_pk_bf16_f32 %0, %1, %2" : "=v"(u1) : "v"(st[ni][mi][2]), "v"(st[ni][mi][3]));
          int Lb = (ni*16 + g*4) * 2;
          *(unsigned*)(smem + rb + ((Lb    ) ^ sw)) = u0;
          *(unsigned*)(smem + rb + ((Lb + 4) ^ sw)) = u1;
        }
      }

      // ---- O^T += Vt * P^T  (reads identical to R2's verified patterns)
      __builtin_amdgcn_s_setprio(1);
#pragma unroll
      for (int kk = 0; kk < 2; ++kk) {
        bf16x8 pb[2];
#pragma unroll
        for (int mi = 0; mi < 2; ++mi) {
          int pr = mi*16 + c;
          int Lb = pr*128 + (kk*32 + g*8)*2;
          pb[mi] = *(const bf16x8*)(smem + pbase + (Lb ^ ((pr & 7) << 4)));
        }
        bf16x8 bv[4];
#pragma unroll
        for (int nd = 0; nd < 4; ++nd) {
          int vr = nd*16 + c;                      // d index
          int Lb = vr*128 + (kk*32 + g*8)*2;       // kv offset contiguous
          bv[nd] = *(const bf16x8*)(smem + cur + 8192 + (Lb ^ ((vr & 7) << 4)));
        }
#pragma unroll
        for (int nd = 0; nd < 4; ++nd)
#pragma unroll
          for (int mi = 0; mi < 2; ++mi)
            po[nd][mi] = __builtin_amdgcn_mfma_f32_16x16x32_bf16(bv[nd], pb[mi], po[nd][mi], 0, 0, 0);
      }
      __builtin_amdgcn_s_setprio(0);
    }
    __syncthreads();   // drains staging loads; protects buffers
  }

  // ---- normalize + store y as (B*T, C) bf16; O^T: lane q = mi*16+c, d = nd*16+g*4+r
  const int b = bh >> 4, h = bh & 15;
#pragma unroll
  for (int mi = 0; mi < 2; ++mi) {
    float inv = 1.f / lrun[mi];
    int t = q0w + mi*16 + c;
#pragma unroll
    for (int nd = 0; nd < 4; ++nd) {
      ushort4 o;
      o.x = f2bf(po[nd][mi][0] * inv);
      o.y = f2bf(po[nd][mi][1] * inv);
      o.z = f2bf(po[nd][mi][2] * inv);
      o.w = f2bf(po[nd][mi][3] * inv);
      *(ushort4*)(yb + ((size_t)b*T_ + t)*C_ + h*64 + nd*16 + g*4) = o;
    }
  }
}

// ---------------------------------------------------------------- launcher
extern "C" void kernel_launch(void* const* d_in, const int* in_sizes, int n_in,
                              void* d_out, int out_size, void* d_ws, size_t ws_size,
                              hipStream_t stream)
{
  const float* x  = (const float*)d_in[0];
  const float* Wq = (const float*)d_in[1];
  const float* Wk = (const float*)d_in[2];
  const float* Wv = (const float*)d_in[3];
  const float* Wp = (const float*)d_in[4];
  const int*   sp = (const int*)d_in[5];
  float* out = (float*)d_out;

  char* ws = (char*)d_ws;
  unsigned short* xb   = (unsigned short*)(ws);                  // 16 MB
  unsigned short* wcat = (unsigned short*)(ws + 16777216);       // 6 MB [Wq;Wk;Wv]
  unsigned short* wpb  = (unsigned short*)(ws + 23068672);       // 2 MB
  unsigned short* qb   = (unsigned short*)(ws + 25165824);       // 16 MB (B,H,T,D)
  unsigned short* kb   = (unsigned short*)(ws + 41943040);       // 16 MB (B,H,T,D)
  unsigned short* vt   = (unsigned short*)(ws + 58720256);       // 16 MB (B,H,D,T)
  unsigned short* yb   = (unsigned short*)(ws + 75497472);       // 16 MB (B*T, C)
  float* cosT = (float*)(ws + 92274688);                         // 512 KB
  float* sinT = (float*)(ws + 92798976);                         // 512 KB

  k_convert<<<dim3(2048), dim3(256), 0, stream>>>(x, Wq, Wk, Wv, Wp, xb, wcat, wpb);
  k_rope_tab<<<dim3(512), dim3(256), 0, stream>>>(sp, cosT, sinT);
  k_gemm<0><<<dim3(64, 24), dim3(256), 0, stream>>>(xb, wcat, qb, kb, vt, cosT, sinT, nullptr);
  k_attn<<<dim3(16, 64), dim3(256), 0, stream>>>(qb, kb, vt, yb);
  k_gemm<1><<<dim3(64, 8), dim3(256), 0, stream>>>(yb, wpb, nullptr, nullptr, nullptr, nullptr, nullptr, out);
}

// Round 5
// 237.502 us; speedup vs baseline: 1.4937x; 1.0258x over previous
//
#include <hip/hip_runtime.h>
#include <hip/hip_bf16.h>
#include <stdint.h>

// Problem constants
#define B_  4
#define T_  2048
#define C_  1024
#define H_  16
#define D_  64
#define BT  (B_*T_)     // 8192
#define KDIM 1024

typedef __attribute__((ext_vector_type(8))) short bf16x8;
typedef __attribute__((ext_vector_type(4))) float f32x4;

__device__ __forceinline__ unsigned short f2bf(float f) {
  union { float f; unsigned u; } v; v.f = f;
  unsigned r = v.u + 0x7FFFu + ((v.u >> 16) & 1u);   // RNE
  return (unsigned short)(r >> 16);
}

__device__ __forceinline__ float exp2_fast(float x) {   // raw v_exp_f32 (2^x)
  float r;
  asm("v_exp_f32 %0, %1" : "=v"(r) : "v"(x));
  return r;
}

// async global->LDS, 16B per lane. dest must be wave-uniform base + lane*16 (linear).
__device__ __forceinline__ void gld_lds16(const void* g, void* l) {
  __builtin_amdgcn_global_load_lds(
      (__attribute__((address_space(1))) unsigned int*)(uintptr_t)g,
      (__attribute__((address_space(3))) unsigned int*)(unsigned)(uintptr_t)l,
      16, 0, 0);
}

// ---------------------------------------------------------------- prep kernels
__global__ __launch_bounds__(256) void k_convert(
    const float* __restrict__ x,  const float* __restrict__ wq,
    const float* __restrict__ wk, const float* __restrict__ wv,
    const float* __restrict__ wp,
    unsigned short* __restrict__ xb, unsigned short* __restrict__ wcat,
    unsigned short* __restrict__ wpb)
{
  const int NX = BT*C_/4;       // 2097152 float4s of x
  const int NW = C_*C_/4;       // 262144 per W
  const int TOT = NX + 4*NW;
  for (int i = blockIdx.x*blockDim.x + threadIdx.x; i < TOT; i += gridDim.x*blockDim.x) {
    const float4* src; unsigned short* dst; int idx;
    if (i < NX)                { src = (const float4*)x;  dst = xb;            idx = i; }
    else {
      int j = i - NX;
      if (j < NW)              { src = (const float4*)wq; dst = wcat;          idx = j; }
      else if (j < 2*NW)       { src = (const float4*)wk; dst = wcat + C_*C_;  idx = j - NW; }
      else if (j < 3*NW)       { src = (const float4*)wv; dst = wcat + 2*C_*C_;idx = j - 2*NW; }
      else                     { src = (const float4*)wp; dst = wpb;           idx = j - 3*NW; }
    }
    float4 v = src[idx];
    ushort4 o; o.x = f2bf(v.x); o.y = f2bf(v.y); o.z = f2bf(v.z); o.w = f2bf(v.w);
    *(ushort4*)(dst + (size_t)idx*4) = o;
  }
}

// Reference quirk: emb = concat([freqs,freqs]) -> angle for element j is t*invf[j%32],
// while rotate_half is interleaved (partner = j^1).
// Tables stored TRANSPOSED [D][T] so the GEMM epilogue (4 consecutive t per
// accumulator, fixed d) loads them as float4.
__global__ __launch_bounds__(256) void k_rope_tab(
    const int* __restrict__ start_pos, float* __restrict__ cosTT, float* __restrict__ sinTT)
{
  int i = blockIdx.x*blockDim.x + threadIdx.x;   // [0, T_*64)
  if (i >= T_*D_) return;
  int t = i >> 6, j = i & 63;
  float inv = exp2f(-(float)(j & 31) * (13.287712379549449f / 32.0f));
  float ang = (float)(t + start_pos[0]) * inv;
  cosTT[(size_t)j*T_ + t] = cosf(ang);
  sinTT[(size_t)j*T_ + t] = sinf(ang);
}

// ---------------------------------------------------------------- GEMM (NT, bf16)
// C[m,n] = sum_k A[m,k]*Bw[n,k].  128x128 tile, BK=64, 4 waves (2x2), mfma 16x16x32.
// EPI 0: fused RoPE -> qb/kb (B,H,T,D) bf16 (q pre-scaled by log2e/8), v
//        transposed -> vt (B,H,D,T) bf16 via 8B ushort4 stores.
// EPI 1: plain f32 store to outF.
template<int EPI>
__global__ __launch_bounds__(256) void k_gemm(
    const unsigned short* __restrict__ A, const unsigned short* __restrict__ Bw,
    unsigned short* __restrict__ qb, unsigned short* __restrict__ kb,
    unsigned short* __restrict__ vt,
    const float* __restrict__ cosTT, const float* __restrict__ sinTT,
    float* __restrict__ outF)
{
  __shared__ __attribute__((aligned(16))) char smem[32768];  // A:16K B:16K
  const int tid = threadIdx.x, l = tid & 63, w = tid >> 6;
  const int g = l >> 4, c = l & 15;
  const int m0 = blockIdx.x * 128, n0 = blockIdx.y * 128;
  const int wr = w >> 1, wc = w & 1;

  const char* srcA[4]; const char* srcB[4]; int dstP[4];
#pragma unroll
  for (int j = 0; j < 4; ++j) {
    int P = w*4096 + j*1024 + l*16;
    int row = P >> 7;
    int Lb = P ^ ((row & 7) << 4);
    int col = (Lb & 127) >> 1;
    dstP[j] = P;
    srcA[j] = (const char*)A  + ((size_t)(m0 + row) * KDIM + col) * 2;
    srcB[j] = (const char*)Bw + ((size_t)(n0 + row) * KDIM + col) * 2;
  }

  f32x4 acc[4][4];
#pragma unroll
  for (int i = 0; i < 4; ++i)
#pragma unroll
    for (int j = 0; j < 4; ++j) acc[i][j] = (f32x4){0.f,0.f,0.f,0.f};

  for (int kt = 0; kt < KDIM; kt += 64) {
#pragma unroll
    for (int j = 0; j < 4; ++j) {
      gld_lds16(srcA[j] + kt*2, smem + dstP[j]);
      gld_lds16(srcB[j] + kt*2, smem + 16384 + dstP[j]);
    }
    __syncthreads();
#pragma unroll
    for (int kk = 0; kk < 2; ++kk) {
      bf16x8 af[4], bw4[4];
#pragma unroll
      for (int mi = 0; mi < 4; ++mi) {
        int row = wr*64 + mi*16 + c;
        int Lb = row*128 + (kk*32 + g*8)*2;
        af[mi] = *(const bf16x8*)(smem + (Lb ^ ((row & 7) << 4)));
      }
#pragma unroll
      for (int ni = 0; ni < 4; ++ni) {
        int row = wc*64 + ni*16 + c;
        int Lb = row*128 + (kk*32 + g*8)*2;
        bw4[ni] = *(const bf16x8*)(smem + 16384 + (Lb ^ ((row & 7) << 4)));
      }
#pragma unroll
      for (int mi = 0; mi < 4; ++mi)
#pragma unroll
        for (int ni = 0; ni < 4; ++ni)
          acc[mi][ni] = __builtin_amdgcn_mfma_f32_16x16x32_bf16(af[mi], bw4[ni], acc[mi][ni], 0, 0, 0);
    }
    __syncthreads();
  }

  // epilogue; C layout: col = lane&15, row = (lane>>4)*4 + r
#pragma unroll
  for (int mi = 0; mi < 4; ++mi) {
#pragma unroll
    for (int ni = 0; ni < 4; ++ni) {
      const int mrow0 = m0 + wr*64 + mi*16 + g*4;
      const int ncol  = n0 + wc*64 + ni*16 + c;
      if (EPI == 1) {
#pragma unroll
        for (int r = 0; r < 4; ++r)
          outF[(size_t)(mrow0 + r) * 1024 + ncol] = acc[mi][ni][r];
      } else {
        const int which = ncol >> 10;          // 0=q 1=k 2=v (wave-uniform)
        const int d = ncol & 1023, h = d >> 6, dd = d & 63;
        const int b = mrow0 >> 11, t0 = mrow0 & 2047;
        if (which == 2) {
          ushort4 o;
          o.x = f2bf(acc[mi][ni][0]); o.y = f2bf(acc[mi][ni][1]);
          o.z = f2bf(acc[mi][ni][2]); o.w = f2bf(acc[mi][ni][3]);
          *(ushort4*)(vt + ((size_t)((b*H_ + h)*D_ + dd))*T_ + t0) = o;
        } else {
          float4 cv4 = *(const float4*)(cosTT + (size_t)dd*T_ + t0);
          float4 sv4 = *(const float4*)(sinTT + (size_t)dd*T_ + t0);
#pragma unroll
          for (int r = 0; r < 4; ++r) {
            float val = acc[mi][ni][r];
            float partner = __shfl_xor(val, 1);          // value at dd^1 (lane^1)
            float rot = (dd & 1) ? partner : -partner;   // interleaved rotate_half
            float cv = (r==0)?cv4.x:(r==1)?cv4.y:(r==2)?cv4.z:cv4.w;
            float sv = (r==0)?sv4.x:(r==1)?sv4.y:(r==2)?sv4.z:sv4.w;
            float o = val*cv + rot*sv;
            size_t oidx = (((size_t)(b*H_ + h))*T_ + (t0 + r))*D_ + dd;
            // q pre-scale: 1/sqrt(64) * log2(e)  (softmax done in exp2 domain)
            if (which == 0) qb[oidx] = f2bf(o * 0.180336879f);
            else            kb[oidx] = f2bf(o);
          }
        }
      }
    }
  }
}

// ---------------------------------------------------------------- flash attention
// Transposed-S structure: S^T = mfma(K, Q); lane owns whole q-rows (q = lane&15).
// exp2-domain softmax (scale folded into q), raw v_exp_f32.
// Defer-max (THR=8): skip po/lrun rescale unless __any(mt > m+8).
// Per-lane partial row-sums; cross-g sum reduce once in epilogue.
// P^T packed via v_cvt_pk_bf16_f32, written as b64 (uint2) swizzled stores.
__global__ __launch_bounds__(256) void k_attn(
    const unsigned short* __restrict__ qb, const unsigned short* __restrict__ kb,
    const unsigned short* __restrict__ vt, unsigned short* __restrict__ yb)
{
  __shared__ __attribute__((aligned(16))) char smem[49152]; // 2x(K:8K V:8K) + P:16K
  const int tid = threadIdx.x, l = tid & 63, w = tid >> 6;
  const int g = l >> 4, c = l & 15;
  const int bh = blockIdx.y;
  const int qt = (int)gridDim.x - 1 - (int)blockIdx.x;  // heavy tiles first
  const int q0 = qt * 128;
  const int q0w = q0 + w*32;                            // this wave's q rows
  const size_t bhO = (size_t)bh * T_ * D_;
  const int pbase = 32768 + w*4096;

  // Q fragments in registers (q pre-scaled by log2e/8)
  bf16x8 aq[2][2];
#pragma unroll
  for (int mi = 0; mi < 2; ++mi)
#pragma unroll
    for (int kc = 0; kc < 2; ++kc) {
      int row = q0w + mi*16 + c;
      aq[mi][kc] = *(const bf16x8*)(qb + bhO + (size_t)row*D_ + kc*32 + g*8);
    }

  f32x4 po[4][2];                 // O^T: [nd][mi], lane: d=nd*16+g*4+r, q=mi*16+c
  float mrun[2], lrun[2];
#pragma unroll
  for (int nd = 0; nd < 4; ++nd)
#pragma unroll
    for (int mi = 0; mi < 2; ++mi) po[nd][mi] = (f32x4){0.f,0.f,0.f,0.f};
  mrun[0] = mrun[1] = -1e30f; lrun[0] = lrun[1] = 0.f;

  // staging descriptors (2 x 16B per thread for K, 2 for Vt)
  const char* srcK[2]; const char* srcV[2]; int dstP2[2];
#pragma unroll
  for (int j = 0; j < 2; ++j) {
    int P = w*2048 + j*1024 + l*16;
    int row = P >> 7;                       // K: kv index   Vt: d index
    int Lb = P ^ ((row & 7) << 4);
    int col = (Lb & 127) >> 1;              // K: d offset   Vt: kv offset
    dstP2[j] = P;
    srcK[j] = (const char*)(kb + bhO) + ((size_t)row*D_ + col)*2;   // + kv0*128B/iter
    srcV[j] = (const char*)(vt + bhO) + ((size_t)row*T_ + col)*2;   // + kv0*2B/iter
  }

  const int nkt = (q0 + 128) >> 6;

  // prologue: stage tile 0 into buffer 0
#pragma unroll
  for (int j = 0; j < 2; ++j) {
    gld_lds16(srcK[j], smem + dstP2[j]);
    gld_lds16(srcV[j], smem + 8192 + dstP2[j]);
  }
  __syncthreads();

  for (int it = 0; it < nkt; ++it) {
    const int kv0 = it * 64;
    const int cur = (it & 1) * 16384;
    // stage next tile into the other buffer (hidden under compute)
    if (it + 1 < nkt) {
      const int nxt = 16384 - cur;
      const size_t ko = (size_t)(kv0 + 64) * 128;
      const size_t vo = (size_t)(kv0 + 64) * 2;
#pragma unroll
      for (int j = 0; j < 2; ++j) {
        gld_lds16(srcK[j] + ko, smem + nxt + dstP2[j]);
        gld_lds16(srcV[j] + vo, smem + nxt + 8192 + dstP2[j]);
      }
    }

    if (kv0 < q0w + 32) {          // tile has at least one unmasked element
      // ---- S^T = K Q^T  (64 kv x 32 q per wave)
      f32x4 st[4][2];
#pragma unroll
      for (int ni = 0; ni < 4; ++ni)
#pragma unroll
        for (int mi = 0; mi < 2; ++mi) st[ni][mi] = (f32x4){0.f,0.f,0.f,0.f};
      __builtin_amdgcn_s_setprio(1);
#pragma unroll
      for (int kk = 0; kk < 2; ++kk) {
        bf16x8 bk[4];
#pragma unroll
        for (int ni = 0; ni < 4; ++ni) {
          int kn = ni*16 + c;
          int Lb = kn*128 + (kk*32 + g*8)*2;
          bk[ni] = *(const bf16x8*)(smem + cur + (Lb ^ ((kn & 7) << 4)));
        }
#pragma unroll
        for (int ni = 0; ni < 4; ++ni)
#pragma unroll
          for (int mi = 0; mi < 2; ++mi)
            st[ni][mi] = __builtin_amdgcn_mfma_f32_16x16x32_bf16(bk[ni], aq[mi][kk], st[ni][mi], 0, 0, 0);
      }
      __builtin_amdgcn_s_setprio(0);

      // ---- causal mask (partial tiles only; wave-uniform branch)
      if (kv0 + 64 > q0w) {
#pragma unroll
        for (int ni = 0; ni < 4; ++ni)
#pragma unroll
          for (int r = 0; r < 4; ++r) {
            int kvv = kv0 + ni*16 + g*4 + r;
#pragma unroll
            for (int mi = 0; mi < 2; ++mi) {
              int qq = q0w + mi*16 + c;
              if (kvv > qq) st[ni][mi][r] = -1e30f;
            }
          }
      }

      // ---- online softmax (exp2 domain, defer-max, per-lane partial sums)
#pragma unroll
      for (int mi = 0; mi < 2; ++mi) {
        float mt = -1e30f;
#pragma unroll
        for (int ni = 0; ni < 4; ++ni)
#pragma unroll
          for (int r = 0; r < 4; ++r) mt = fmaxf(mt, st[ni][mi][r]);
        mt = fmaxf(mt, __shfl_xor(mt, 16));
        mt = fmaxf(mt, __shfl_xor(mt, 32));
        float m_use = mrun[mi];
        if (__any(mt > m_use + 8.f)) {
          float mnew = fmaxf(m_use, mt);
          float alpha = exp2_fast(m_use - mnew);
          mrun[mi] = mnew;
          m_use = mnew;
          lrun[mi] *= alpha;
#pragma unroll
          for (int nd = 0; nd < 4; ++nd)
#pragma unroll
            for (int r = 0; r < 4; ++r) po[nd][mi][r] *= alpha;
        }
        float rs = 0.f;
#pragma unroll
        for (int ni = 0; ni < 4; ++ni)
#pragma unroll
          for (int r = 0; r < 4; ++r) {
            float p = exp2_fast(st[ni][mi][r] - m_use);
            st[ni][mi][r] = p;
            rs += p;
          }
        lrun[mi] += rs;   // per-lane partial (16 kv); cross-g reduce at end
      }

      // ---- P^T -> LDS (packed pairs, b64 swizzled stores, wave-private)
#pragma unroll
      for (int mi = 0; mi < 2; ++mi) {
        const int row = mi*16 + c;
        const int sw = (row & 7) << 4;
        const int rb = pbase + row*128;
#pragma unroll
        for (int ni = 0; ni < 4; ++ni) {
          unsigned u0, u1;
          asm("v_cvt_pk_bf16_f32 %0, %1, %2" : "=v"(u0) : "v"(st[ni][mi][0]), "v"(st[ni][mi][1]));
          asm("v_cvt_pk_bf16_f32 %0, %1, %2" : "=v"(u1) : "v"(st[ni][mi][2]), "v"(st[ni][mi][3]));
          int Lb = (ni*16 + g*4) * 2;      // 8B-aligned; sw flips bits 4-6 only
          uint2 uu; uu.x = u0; uu.y = u1;
          *(uint2*)(smem + rb + (Lb ^ sw)) = uu;
        }
      }

      // ---- O^T += Vt * P^T
      __builtin_amdgcn_s_setprio(1);
#pragma unroll
      for (int kk = 0; kk < 2; ++kk) {
        bf16x8 pb[2];
#pragma unroll
        for (int mi = 0; mi < 2; ++mi) {
          int pr = mi*16 + c;
          int Lb = pr*128 + (kk*32 + g*8)*2;
          pb[mi] = *(const bf16x8*)(smem + pbase + (Lb ^ ((pr & 7) << 4)));
        }
        bf16x8 bv[4];
#pragma unroll
        for (int nd = 0; nd < 4; ++nd) {
          int vr = nd*16 + c;                      // d index
          int Lb = vr*128 + (kk*32 + g*8)*2;       // kv offset contiguous
          bv[nd] = *(const bf16x8*)(smem + cur + 8192 + (Lb ^ ((vr & 7) << 4)));
        }
#pragma unroll
        for (int nd = 0; nd < 4; ++nd)
#pragma unroll
          for (int mi = 0; mi < 2; ++mi)
            po[nd][mi] = __builtin_amdgcn_mfma_f32_16x16x32_bf16(bv[nd], pb[mi], po[nd][mi], 0, 0, 0);
      }
      __builtin_amdgcn_s_setprio(0);
    }
    __syncthreads();   // drains staging loads; protects buffers
  }

  // ---- normalize + store y as (B*T, C) bf16; O^T: lane q = mi*16+c, d = nd*16+g*4+r
  const int b = bh >> 4, h = bh & 15;
#pragma unroll
  for (int mi = 0; mi < 2; ++mi) {
    float ls = lrun[mi];
    ls += __shfl_xor(ls, 16);
    ls += __shfl_xor(ls, 32);
    float inv = 1.f / ls;
    int t = q0w + mi*16 + c;
#pragma unroll
    for (int nd = 0; nd < 4; ++nd) {
      ushort4 o;
      o.x = f2bf(po[nd][mi][0] * inv);
      o.y = f2bf(po[nd][mi][1] * inv);
      o.z = f2bf(po[nd][mi][2] * inv);
      o.w = f2bf(po[nd][mi][3] * inv);
      *(ushort4*)(yb + ((size_t)b*T_ + t)*C_ + h*64 + nd*16 + g*4) = o;
    }
  }
}

// ---------------------------------------------------------------- launcher
extern "C" void kernel_launch(void* const* d_in, const int* in_sizes, int n_in,
                              void* d_out, int out_size, void* d_ws, size_t ws_size,
                              hipStream_t stream)
{
  const float* x  = (const float*)d_in[0];
  const float* Wq = (const float*)d_in[1];
  const float* Wk = (const float*)d_in[2];
  const float* Wv = (const float*)d_in[3];
  const float* Wp = (const float*)d_in[4];
  const int*   sp = (const int*)d_in[5];
  float* out = (float*)d_out;

  char* ws = (char*)d_ws;
  unsigned short* xb   = (unsigned short*)(ws);                  // 16 MB
  unsigned short* wcat = (unsigned short*)(ws + 16777216);       // 6 MB [Wq;Wk;Wv]
  unsigned short* wpb  = (unsigned short*)(ws + 23068672);       // 2 MB
  unsigned short* qb   = (unsigned short*)(ws + 25165824);       // 16 MB (B,H,T,D)
  unsigned short* kb   = (unsigned short*)(ws + 41943040);       // 16 MB (B,H,T,D)
  unsigned short* vt   = (unsigned short*)(ws + 58720256);       // 16 MB (B,H,D,T)
  unsigned short* yb   = (unsigned short*)(ws + 75497472);       // 16 MB (B*T, C)
  float* cosTT = (float*)(ws + 92274688);                        // 512 KB [D][T]
  float* sinTT = (float*)(ws + 92798976);                        // 512 KB [D][T]

  k_convert<<<dim3(2048), dim3(256), 0, stream>>>(x, Wq, Wk, Wv, Wp, xb, wcat, wpb);
  k_rope_tab<<<dim3(512), dim3(256), 0, stream>>>(sp, cosTT, sinTT);
  k_gemm<0><<<dim3(64, 24), dim3(256), 0, stream>>>(xb, wcat, qb, kb, vt, cosTT, sinTT, nullptr);
  k_attn<<<dim3(16, 64), dim3(256), 0, stream>>>(qb, kb, vt, yb);
  k_gemm<1><<<dim3(64, 8), dim3(256), 0, stream>>>(yb, wpb, nullptr, nullptr, nullptr, nullptr, nullptr, out);
}

// Round 7
// 184.144 us; speedup vs baseline: 1.9266x; 1.2898x over previous
//
#include <hip/hip_runtime.h>
#include <hip/hip_bf16.h>
#include <stdint.h>

// Problem constants
#define B_  4
#define T_  2048
#define C_  1024
#define H_  16
#define D_  64
#define BT  (B_*T_)     // 8192
#define KDIM 1024

typedef __attribute__((ext_vector_type(8))) short bf16x8;
typedef __attribute__((ext_vector_type(4))) float f32x4;

__device__ __forceinline__ unsigned short f2bf(float f) {
  union { float f; unsigned u; } v; v.f = f;
  unsigned r = v.u + 0x7FFFu + ((v.u >> 16) & 1u);   // RNE
  return (unsigned short)(r >> 16);
}

__device__ __forceinline__ float exp2_fast(float x) {   // raw v_exp_f32 (2^x)
  float r;
  asm("v_exp_f32 %0, %1" : "=v"(r) : "v"(x));
  return r;
}

// async global->LDS, 16B per lane. dest must be wave-uniform base + lane*16 (linear).
__device__ __forceinline__ void gld_lds16(const void* g, void* l) {
  __builtin_amdgcn_global_load_lds(
      (__attribute__((address_space(1))) unsigned int*)(uintptr_t)g,
      (__attribute__((address_space(3))) unsigned int*)(unsigned)(uintptr_t)l,
      16, 0, 0);
}

// ---------------------------------------------------------------- prep kernels
__global__ __launch_bounds__(256) void k_convert(
    const float* __restrict__ x,  const float* __restrict__ wq,
    const float* __restrict__ wk, const float* __restrict__ wv,
    const float* __restrict__ wp,
    unsigned short* __restrict__ xb, unsigned short* __restrict__ wcat,
    unsigned short* __restrict__ wpb)
{
  const int NX = BT*C_/4;       // 2097152 float4s of x
  const int NW = C_*C_/4;       // 262144 per W
  const int TOT = NX + 4*NW;
  for (int i = blockIdx.x*blockDim.x + threadIdx.x; i < TOT; i += gridDim.x*blockDim.x) {
    const float4* src; unsigned short* dst; int idx;
    if (i < NX)                { src = (const float4*)x;  dst = xb;            idx = i; }
    else {
      int j = i - NX;
      if (j < NW)              { src = (const float4*)wq; dst = wcat;          idx = j; }
      else if (j < 2*NW)       { src = (const float4*)wk; dst = wcat + C_*C_;  idx = j - NW; }
      else if (j < 3*NW)       { src = (const float4*)wv; dst = wcat + 2*C_*C_;idx = j - 2*NW; }
      else                     { src = (const float4*)wp; dst = wpb;           idx = j - 3*NW; }
    }
    float4 v = src[idx];
    ushort4 o; o.x = f2bf(v.x); o.y = f2bf(v.y); o.z = f2bf(v.z); o.w = f2bf(v.w);
    *(ushort4*)(dst + (size_t)idx*4) = o;
  }
}

// Reference quirk: emb = concat([freqs,freqs]) -> angle for element j is t*invf[j%32],
// while rotate_half is interleaved (partner = j^1). Layout [T][D] (coalesced in
// the GEMM epilogue: lanes vary dd -> contiguous 64B).
__global__ __launch_bounds__(256) void k_rope_tab(
    const int* __restrict__ start_pos, float* __restrict__ cosT, float* __restrict__ sinT)
{
  int i = blockIdx.x*blockDim.x + threadIdx.x;   // [0, T_*64)
  if (i >= T_*D_) return;
  int t = i >> 6, j = i & 63;
  float inv = exp2f(-(float)(j & 31) * (13.287712379549449f / 32.0f));
  float ang = (float)(t + start_pos[0]) * inv;
  cosT[i] = cosf(ang);
  sinT[i] = sinf(ang);
}

// ---------------------------------------------------------------- GEMM (NT, bf16)
// C[m,n] = sum_k A[m,k]*Bw[n,k].  128x128 tile, BK=64, 4 waves (2x2), mfma 16x16x32.
// EPI 0: fused RoPE -> qb/kb (B,H,T,D) bf16 (q pre-scaled by log2e/8), v
//        transposed -> vt (B,H,D,T) bf16 via 8B ushort4 stores.
// EPI 1: plain f32 store to outF.
template<int EPI>
__global__ __launch_bounds__(256) void k_gemm(
    const unsigned short* __restrict__ A, const unsigned short* __restrict__ Bw,
    unsigned short* __restrict__ qb, unsigned short* __restrict__ kb,
    unsigned short* __restrict__ vt,
    const float* __restrict__ cosT, const float* __restrict__ sinT,
    float* __restrict__ outF)
{
  __shared__ __attribute__((aligned(16))) char smem[32768];  // A:16K B:16K
  const int tid = threadIdx.x, l = tid & 63, w = tid >> 6;
  const int g = l >> 4, c = l & 15;
  const int m0 = blockIdx.x * 128, n0 = blockIdx.y * 128;
  const int wr = w >> 1, wc = w & 1;

  const char* srcA[4]; const char* srcB[4]; int dstP[4];
#pragma unroll
  for (int j = 0; j < 4; ++j) {
    int P = w*4096 + j*1024 + l*16;
    int row = P >> 7;
    int Lb = P ^ ((row & 7) << 4);
    int col = (Lb & 127) >> 1;
    dstP[j] = P;
    srcA[j] = (const char*)A  + ((size_t)(m0 + row) * KDIM + col) * 2;
    srcB[j] = (const char*)Bw + ((size_t)(n0 + row) * KDIM + col) * 2;
  }

  f32x4 acc[4][4];
#pragma unroll
  for (int i = 0; i < 4; ++i)
#pragma unroll
    for (int j = 0; j < 4; ++j) acc[i][j] = (f32x4){0.f,0.f,0.f,0.f};

  for (int kt = 0; kt < KDIM; kt += 64) {
#pragma unroll
    for (int j = 0; j < 4; ++j) {
      gld_lds16(srcA[j] + kt*2, smem + dstP[j]);
      gld_lds16(srcB[j] + kt*2, smem + 16384 + dstP[j]);
    }
    __syncthreads();
#pragma unroll
    for (int kk = 0; kk < 2; ++kk) {
      bf16x8 af[4], bw4[4];
#pragma unroll
      for (int mi = 0; mi < 4; ++mi) {
        int row = wr*64 + mi*16 + c;
        int Lb = row*128 + (kk*32 + g*8)*2;
        af[mi] = *(const bf16x8*)(smem + (Lb ^ ((row & 7) << 4)));
      }
#pragma unroll
      for (int ni = 0; ni < 4; ++ni) {
        int row = wc*64 + ni*16 + c;
        int Lb = row*128 + (kk*32 + g*8)*2;
        bw4[ni] = *(const bf16x8*)(smem + 16384 + (Lb ^ ((row & 7) << 4)));
      }
#pragma unroll
      for (int mi = 0; mi < 4; ++mi)
#pragma unroll
        for (int ni = 0; ni < 4; ++ni)
          acc[mi][ni] = __builtin_amdgcn_mfma_f32_16x16x32_bf16(af[mi], bw4[ni], acc[mi][ni], 0, 0, 0);
    }
    __syncthreads();
  }

  // epilogue; C layout: col = lane&15, row = (lane>>4)*4 + r
#pragma unroll
  for (int mi = 0; mi < 4; ++mi) {
#pragma unroll
    for (int ni = 0; ni < 4; ++ni) {
      const int mrow0 = m0 + wr*64 + mi*16 + g*4;
      const int ncol  = n0 + wc*64 + ni*16 + c;
      if (EPI == 1) {
#pragma unroll
        for (int r = 0; r < 4; ++r)
          outF[(size_t)(mrow0 + r) * 1024 + ncol] = acc[mi][ni][r];
      } else {
        const int which = ncol >> 10;          // 0=q 1=k 2=v (wave-uniform)
        const int d = ncol & 1023, h = d >> 6, dd = d & 63;
        const int b = mrow0 >> 11, t0 = mrow0 & 2047;
        if (which == 2) {
          ushort4 o;
          o.x = f2bf(acc[mi][ni][0]); o.y = f2bf(acc[mi][ni][1]);
          o.z = f2bf(acc[mi][ni][2]); o.w = f2bf(acc[mi][ni][3]);
          *(ushort4*)(vt + ((size_t)((b*H_ + h)*D_ + dd))*T_ + t0) = o;
        } else {
#pragma unroll
          for (int r = 0; r < 4; ++r) {
            float val = acc[mi][ni][r];
            float partner = __shfl_xor(val, 1);          // value at dd^1 (lane^1)
            float rot = (dd & 1) ? partner : -partner;   // interleaved rotate_half
            float cv = cosT[(t0 + r)*64 + dd], sv = sinT[(t0 + r)*64 + dd];
            float o = val*cv + rot*sv;
            size_t oidx = (((size_t)(b*H_ + h))*T_ + (t0 + r))*D_ + dd;
            // q pre-scale: 1/sqrt(64) * log2(e)  (softmax done in exp2 domain)
            if (which == 0) qb[oidx] = f2bf(o * 0.180336879f);
            else            kb[oidx] = f2bf(o);
          }
        }
      }
    }
  }
}

// ---------------------------------------------------------------- flash attention
// Transposed-S structure: S^T = mfma(K, Q); lane owns whole q-rows (q = lane&15).
// exp2-domain softmax, defer-max (THR=8), per-lane partial row-sums.
// P^T packed via v_cvt_pk_bf16_f32, b64 swizzled stores. K/Vt double-buffered.
// LOAD BALANCE: each block processes TWO q-tiles {15-p, p} (same bh) -> every
// block runs exactly 34 kv-iters; grid 8x64 = 512 uniform blocks.
__global__ __launch_bounds__(256) void k_attn(
    const unsigned short* __restrict__ qb, const unsigned short* __restrict__ kb,
    const unsigned short* __restrict__ vt, unsigned short* __restrict__ yb)
{
  __shared__ __attribute__((aligned(16))) char smem[49152]; // 2x(K:8K V:8K) + P:16K
  const int tid = threadIdx.x, l = tid & 63, w = tid >> 6;
  const int g = l >> 4, c = l & 15;
  const int bh = blockIdx.y;
  const size_t bhO = (size_t)bh * T_ * D_;
  const int pbase = 32768 + w*4096;
  const int b = bh >> 4, h = bh & 15;

  // staging descriptors (2 x 16B per thread for K, 2 for Vt) — bh-fixed
  const char* srcK[2]; const char* srcV[2]; int dstP2[2];
#pragma unroll
  for (int j = 0; j < 2; ++j) {
    int P = w*2048 + j*1024 + l*16;
    int row = P >> 7;                       // K: kv index   Vt: d index
    int Lb = P ^ ((row & 7) << 4);
    int col = (Lb & 127) >> 1;              // K: d offset   Vt: kv offset
    dstP2[j] = P;
    srcK[j] = (const char*)(kb + bhO) + ((size_t)row*D_ + col)*2;   // + kv0*128B/iter
    srcV[j] = (const char*)(vt + bhO) + ((size_t)row*T_ + col)*2;   // + kv0*2B/iter
  }

  for (int half = 0; half < 2; ++half) {
    const int qt = half ? (int)blockIdx.x : (15 - (int)blockIdx.x);
    const int q0 = qt * 128;
    const int q0w = q0 + w*32;                          // this wave's q rows

    // Q fragments in registers (q pre-scaled by log2e/8)
    bf16x8 aq[2][2];
#pragma unroll
    for (int mi = 0; mi < 2; ++mi)
#pragma unroll
      for (int kc = 0; kc < 2; ++kc) {
        int row = q0w + mi*16 + c;
        aq[mi][kc] = *(const bf16x8*)(qb + bhO + (size_t)row*D_ + kc*32 + g*8);
      }

    f32x4 po[4][2];               // O^T: [nd][mi], lane: d=nd*16+g*4+r, q=mi*16+c
    float mrun[2], lrun[2];
#pragma unroll
    for (int nd = 0; nd < 4; ++nd)
#pragma unroll
      for (int mi = 0; mi < 2; ++mi) po[nd][mi] = (f32x4){0.f,0.f,0.f,0.f};
    mrun[0] = mrun[1] = -1e30f; lrun[0] = lrun[1] = 0.f;

    const int nkt = (q0 + 128) >> 6;

    // prologue: stage tile 0 into buffer 0 (buf0 is idle here: the previous
    // q-tile's final iter used buf1 [nkt even], and the iter-loop's trailing
    // __syncthreads ordered all its reads before this point)
#pragma unroll
    for (int j = 0; j < 2; ++j) {
      gld_lds16(srcK[j], smem + dstP2[j]);
      gld_lds16(srcV[j], smem + 8192 + dstP2[j]);
    }
    __syncthreads();

    for (int it = 0; it < nkt; ++it) {
      const int kv0 = it * 64;
      const int cur = (it & 1) * 16384;
      // stage next tile into the other buffer (hidden under compute)
      if (it + 1 < nkt) {
        const int nxt = 16384 - cur;
        const size_t ko = (size_t)(kv0 + 64) * 128;
        const size_t vo = (size_t)(kv0 + 64) * 2;
#pragma unroll
        for (int j = 0; j < 2; ++j) {
          gld_lds16(srcK[j] + ko, smem + nxt + dstP2[j]);
          gld_lds16(srcV[j] + vo, smem + nxt + 8192 + dstP2[j]);
        }
      }

      if (kv0 < q0w + 32) {          // tile has at least one unmasked element
        // ---- S^T = K Q^T  (64 kv x 32 q per wave)
        f32x4 st[4][2];
#pragma unroll
        for (int ni = 0; ni < 4; ++ni)
#pragma unroll
          for (int mi = 0; mi < 2; ++mi) st[ni][mi] = (f32x4){0.f,0.f,0.f,0.f};
        __builtin_amdgcn_s_setprio(1);
#pragma unroll
        for (int kk = 0; kk < 2; ++kk) {
          bf16x8 bk[4];
#pragma unroll
          for (int ni = 0; ni < 4; ++ni) {
            int kn = ni*16 + c;
            int Lb = kn*128 + (kk*32 + g*8)*2;
            bk[ni] = *(const bf16x8*)(smem + cur + (Lb ^ ((kn & 7) << 4)));
          }
#pragma unroll
          for (int ni = 0; ni < 4; ++ni)
#pragma unroll
            for (int mi = 0; mi < 2; ++mi)
              st[ni][mi] = __builtin_amdgcn_mfma_f32_16x16x32_bf16(bk[ni], aq[mi][kk], st[ni][mi], 0, 0, 0);
        }
        __builtin_amdgcn_s_setprio(0);

        // ---- causal mask (partial tiles only; wave-uniform branch)
        if (kv0 + 64 > q0w) {
#pragma unroll
          for (int ni = 0; ni < 4; ++ni)
#pragma unroll
            for (int r = 0; r < 4; ++r) {
              int kvv = kv0 + ni*16 + g*4 + r;
#pragma unroll
              for (int mi = 0; mi < 2; ++mi) {
                int qq = q0w + mi*16 + c;
                if (kvv > qq) st[ni][mi][r] = -1e30f;
              }
            }
        }

        // ---- online softmax (exp2 domain, defer-max, per-lane partial sums)
#pragma unroll
        for (int mi = 0; mi < 2; ++mi) {
          float mt = -1e30f;
#pragma unroll
          for (int ni = 0; ni < 4; ++ni)
#pragma unroll
            for (int r = 0; r < 4; ++r) mt = fmaxf(mt, st[ni][mi][r]);
          mt = fmaxf(mt, __shfl_xor(mt, 16));
          mt = fmaxf(mt, __shfl_xor(mt, 32));
          float m_use = mrun[mi];
          if (__any(mt > m_use + 8.f)) {
            float mnew = fmaxf(m_use, mt);
            float alpha = exp2_fast(m_use - mnew);
            mrun[mi] = mnew;
            m_use = mnew;
            lrun[mi] *= alpha;
#pragma unroll
            for (int nd = 0; nd < 4; ++nd)
#pragma unroll
              for (int r = 0; r < 4; ++r) po[nd][mi][r] *= alpha;
          }
          float rs = 0.f;
#pragma unroll
          for (int ni = 0; ni < 4; ++ni)
#pragma unroll
            for (int r = 0; r < 4; ++r) {
              float p = exp2_fast(st[ni][mi][r] - m_use);
              st[ni][mi][r] = p;
              rs += p;
            }
          lrun[mi] += rs;   // per-lane partial (16 kv); cross-g reduce at end
        }

        // ---- P^T -> LDS (packed pairs, b64 swizzled stores, wave-private)
#pragma unroll
        for (int mi = 0; mi < 2; ++mi) {
          const int row = mi*16 + c;
          const int sw = (row & 7) << 4;
          const int rb = pbase + row*128;
#pragma unroll
          for (int ni = 0; ni < 4; ++ni) {
            unsigned u0, u1;
            asm("v_cvt_pk_bf16_f32 %0, %1, %2" : "=v"(u0) : "v"(st[ni][mi][0]), "v"(st[ni][mi][1]));
            asm("v_cvt_pk_bf16_f32 %0, %1, %2" : "=v"(u1) : "v"(st[ni][mi][2]), "v"(st[ni][mi][3]));
            int Lb = (ni*16 + g*4) * 2;      // 8B-aligned; sw flips bits 4-6 only
            uint2 uu; uu.x = u0; uu.y = u1;
            *(uint2*)(smem + rb + (Lb ^ sw)) = uu;
          }
        }

        // ---- O^T += Vt * P^T
        __builtin_amdgcn_s_setprio(1);
#pragma unroll
        for (int kk = 0; kk < 2; ++kk) {
          bf16x8 pb[2];
#pragma unroll
          for (int mi = 0; mi < 2; ++mi) {
            int pr = mi*16 + c;
            int Lb = pr*128 + (kk*32 + g*8)*2;
            pb[mi] = *(const bf16x8*)(smem + pbase + (Lb ^ ((pr & 7) << 4)));
          }
          bf16x8 bv[4];
#pragma unroll
          for (int nd = 0; nd < 4; ++nd) {
            int vr = nd*16 + c;                      // d index
            int Lb = vr*128 + (kk*32 + g*8)*2;       // kv offset contiguous
            bv[nd] = *(const bf16x8*)(smem + cur + 8192 + (Lb ^ ((vr & 7) << 4)));
          }
#pragma unroll
          for (int nd = 0; nd < 4; ++nd)
#pragma unroll
            for (int mi = 0; mi < 2; ++mi)
              po[nd][mi] = __builtin_amdgcn_mfma_f32_16x16x32_bf16(bv[nd], pb[mi], po[nd][mi], 0, 0, 0);
        }
        __builtin_amdgcn_s_setprio(0);
      }
      __syncthreads();   // drains staging loads; protects buffers
    }

    // ---- normalize + store y as (B*T, C) bf16; lane q = mi*16+c, d = nd*16+g*4+r
#pragma unroll
    for (int mi = 0; mi < 2; ++mi) {
      float ls = lrun[mi];
      ls += __shfl_xor(ls, 16);
      ls += __shfl_xor(ls, 32);
      float inv = 1.f / ls;
      int t = q0w + mi*16 + c;
#pragma unroll
      for (int nd = 0; nd < 4; ++nd) {
        ushort4 o;
        o.x = f2bf(po[nd][mi][0] * inv);
        o.y = f2bf(po[nd][mi][1] * inv);
        o.z = f2bf(po[nd][mi][2] * inv);
        o.w = f2bf(po[nd][mi][3] * inv);
        *(ushort4*)(yb + ((size_t)b*T_ + t)*C_ + h*64 + nd*16 + g*4) = o;
      }
    }
  }
}

// ---------------------------------------------------------------- launcher
extern "C" void kernel_launch(void* const* d_in, const int* in_sizes, int n_in,
                              void* d_out, int out_size, void* d_ws, size_t ws_size,
                              hipStream_t stream)
{
  const float* x  = (const float*)d_in[0];
  const float* Wq = (const float*)d_in[1];
  const float* Wk = (const float*)d_in[2];
  const float* Wv = (const float*)d_in[3];
  const float* Wp = (const float*)d_in[4];
  const int*   sp = (const int*)d_in[5];
  float* out = (float*)d_out;

  char* ws = (char*)d_ws;
  unsigned short* xb   = (unsigned short*)(ws);                  // 16 MB
  unsigned short* wcat = (unsigned short*)(ws + 16777216);       // 6 MB [Wq;Wk;Wv]
  unsigned short* wpb  = (unsigned short*)(ws + 23068672);       // 2 MB
  unsigned short* qb   = (unsigned short*)(ws + 25165824);       // 16 MB (B,H,T,D)
  unsigned short* kb   = (unsigned short*)(ws + 41943040);       // 16 MB (B,H,T,D)
  unsigned short* vt   = (unsigned short*)(ws + 58720256);       // 16 MB (B,H,D,T)
  unsigned short* yb   = (unsigned short*)(ws + 75497472);       // 16 MB (B*T, C)
  float* cosT = (float*)(ws + 92274688);                         // 512 KB [T][D]
  float* sinT = (float*)(ws + 92798976);                         // 512 KB [T][D]

  k_convert<<<dim3(2048), dim3(256), 0, stream>>>(x, Wq, Wk, Wv, Wp, xb, wcat, wpb);
  k_rope_tab<<<dim3(512), dim3(256), 0, stream>>>(sp, cosT, sinT);
  k_gemm<0><<<dim3(64, 24), dim3(256), 0, stream>>>(xb, wcat, qb, kb, vt, cosT, sinT, nullptr);
  k_attn<<<dim3(8, 64), dim3(256), 0, stream>>>(qb, kb, vt, yb);
  k_gemm<1><<<dim3(64, 8), dim3(256), 0, stream>>>(yb, wpb, nullptr, nullptr, nullptr, nullptr, nullptr, out);
}

// Round 8
// 180.986 us; speedup vs baseline: 1.9602x; 1.0174x over previous
//
#include <hip/hip_runtime.h>
#include <hip/hip_bf16.h>
#include <stdint.h>

// Problem constants
#define B_  4
#define T_  2048
#define C_  1024
#define H_  16
#define D_  64
#define BT  (B_*T_)     // 8192
#define KDIM 1024

typedef __attribute__((ext_vector_type(8))) short bf16x8;
typedef __attribute__((ext_vector_type(4))) float f32x4;

__device__ __forceinline__ unsigned short f2bf(float f) {
  union { float f; unsigned u; } v; v.f = f;
  unsigned r = v.u + 0x7FFFu + ((v.u >> 16) & 1u);   // RNE
  return (unsigned short)(r >> 16);
}

__device__ __forceinline__ float exp2_fast(float x) {   // raw v_exp_f32 (2^x)
  float r;
  asm("v_exp_f32 %0, %1" : "=v"(r) : "v"(x));
  return r;
}

// async global->LDS, 16B per lane. dest must be wave-uniform base + lane*16 (linear).
__device__ __forceinline__ void gld_lds16(const void* g, void* l) {
  __builtin_amdgcn_global_load_lds(
      (__attribute__((address_space(1))) unsigned int*)(uintptr_t)g,
      (__attribute__((address_space(3))) unsigned int*)(unsigned)(uintptr_t)l,
      16, 0, 0);
}

// ---------------------------------------------------------------- prep kernels
__global__ __launch_bounds__(256) void k_convert(
    const float* __restrict__ x,  const float* __restrict__ wq,
    const float* __restrict__ wk, const float* __restrict__ wv,
    const float* __restrict__ wp,
    unsigned short* __restrict__ xb, unsigned short* __restrict__ wcat,
    unsigned short* __restrict__ wpb)
{
  const int NX = BT*C_/4;       // 2097152 float4s of x
  const int NW = C_*C_/4;       // 262144 per W
  const int TOT = NX + 4*NW;
  for (int i = blockIdx.x*blockDim.x + threadIdx.x; i < TOT; i += gridDim.x*blockDim.x) {
    const float4* src; unsigned short* dst; int idx;
    if (i < NX)                { src = (const float4*)x;  dst = xb;            idx = i; }
    else {
      int j = i - NX;
      if (j < NW)              { src = (const float4*)wq; dst = wcat;          idx = j; }
      else if (j < 2*NW)       { src = (const float4*)wk; dst = wcat + C_*C_;  idx = j - NW; }
      else if (j < 3*NW)       { src = (const float4*)wv; dst = wcat + 2*C_*C_;idx = j - 2*NW; }
      else                     { src = (const float4*)wp; dst = wpb;           idx = j - 3*NW; }
    }
    float4 v = src[idx];
    ushort4 o; o.x = f2bf(v.x); o.y = f2bf(v.y); o.z = f2bf(v.z); o.w = f2bf(v.w);
    *(ushort4*)(dst + (size_t)idx*4) = o;
  }
}

// Reference quirk: emb = concat([freqs,freqs]) -> angle for element j is t*invf[j%32],
// while rotate_half is interleaved (partner = j^1). Layout [T][D] (coalesced in
// the GEMM epilogue: lanes vary dd -> contiguous 64B).
__global__ __launch_bounds__(256) void k_rope_tab(
    const int* __restrict__ start_pos, float* __restrict__ cosT, float* __restrict__ sinT)
{
  int i = blockIdx.x*blockDim.x + threadIdx.x;   // [0, T_*64)
  if (i >= T_*D_) return;
  int t = i >> 6, j = i & 63;
  float inv = exp2f(-(float)(j & 31) * (13.287712379549449f / 32.0f));
  float ang = (float)(t + start_pos[0]) * inv;
  cosT[i] = cosf(ang);
  sinT[i] = sinf(ang);
}

// ---------------------------------------------------------------- 256x256 8-wave GEMM (QKV + RoPE)
// C[m,n] = sum_k A[m,k]*Bw[n,k]. BM=BN=256, BK=64, 512 thr / 8 waves (2M x 4N).
// Per wave: 128x64 output = acc[8][4] f32x4. LDS: double-buffered A(32K)+B(32K)=128KB,
// rows of 128B with byte ^= ((row&7)<<4) swizzle (proven, 0 bank conflicts).
// 4 phases per K-tile, 16 MFMA each; B-frags hoisted at phase 0.
// Issue-early dbuf staging: next A at phase 0, next B at phase 1 -> at the next
// tile's vmcnt(0) gate every load is >=3 phases old (no drain stall).
__global__ __launch_bounds__(512, 2) void k_gemm256(
    const unsigned short* __restrict__ A, const unsigned short* __restrict__ Bw,
    unsigned short* __restrict__ qb, unsigned short* __restrict__ kb,
    unsigned short* __restrict__ vt,
    const float* __restrict__ cosT, const float* __restrict__ sinT)
{
  __shared__ __attribute__((aligned(16))) char smem[131072]; // A0|B0|A1|B1 32KB each
  const int tid = threadIdx.x, l = tid & 63, w = tid >> 6;
  const int g = l >> 4, c = l & 15;
  const int m0 = blockIdx.x * 256, n0 = blockIdx.y * 256;
  const int wr = w >> 2, wc = w & 3;

  // staging descriptors: 4 A + 4 B loads of 16B per thread per K-tile
  const char* srcA[4]; const char* srcB[4]; int dstP[4];
#pragma unroll
  for (int j = 0; j < 4; ++j) {
    int P = j*8192 + tid*16;          // [0, 32768)
    int row = P >> 7;                 // 0..255
    int Lb = P ^ ((row & 7) << 4);
    int col = (Lb & 127) >> 1;        // 0..63
    dstP[j] = P;
    srcA[j] = (const char*)A  + ((size_t)(m0 + row) * KDIM + col) * 2;
    srcB[j] = (const char*)Bw + ((size_t)(n0 + row) * KDIM + col) * 2;
  }

  f32x4 acc[8][4];
#pragma unroll
  for (int i = 0; i < 8; ++i)
#pragma unroll
    for (int j = 0; j < 4; ++j) acc[i][j] = (f32x4){0.f,0.f,0.f,0.f};

  // prologue: issue K-tile 0 into buffer 0
#pragma unroll
  for (int j = 0; j < 4; ++j) {
    gld_lds16(srcA[j], smem + dstP[j]);
    gld_lds16(srcB[j], smem + 32768 + dstP[j]);
  }

#define GPHASE(mb)                                                              \
  {                                                                             \
    bf16x8 af_[2][2];                                                           \
    _Pragma("unroll")                                                           \
    for (int m2 = 0; m2 < 2; ++m2)                                              \
      _Pragma("unroll")                                                         \
      for (int kk = 0; kk < 2; ++kk) {                                          \
        int row = wr*128 + ((mb) + m2)*16 + c;                                  \
        int Lb = row*128 + (kk*32 + g*8)*2;                                     \
        af_[m2][kk] = *(const bf16x8*)(smem + cur + (Lb ^ ((row & 7) << 4)));   \
      }                                                                         \
    __builtin_amdgcn_s_setprio(1);                                              \
    _Pragma("unroll")                                                           \
    for (int m2 = 0; m2 < 2; ++m2)                                              \
      _Pragma("unroll")                                                         \
      for (int ni = 0; ni < 4; ++ni)                                            \
        _Pragma("unroll")                                                       \
        for (int kk = 0; kk < 2; ++kk)                                          \
          acc[(mb)+m2][ni] = __builtin_amdgcn_mfma_f32_16x16x32_bf16(           \
              af_[m2][kk], bwf[ni][kk], acc[(mb)+m2][ni], 0, 0, 0);             \
    __builtin_amdgcn_s_setprio(0);                                              \
  }

  for (int t = 0; t < 16; ++t) {
    const int cur = (t & 1) << 16;    // 0 or 65536
    const int nxt = cur ^ 65536;
    const int ko = (t + 1) * 128;     // next K-tile: +64 els = +128 B along K

    // gate: tile t's loads landed (own vmcnt) + all waves past tile t-1 (barrier)
    asm volatile("s_waitcnt vmcnt(0)" ::: "memory");
    __builtin_amdgcn_s_barrier();

    // ---- phase 0: stage next-A; read all B-frags + A mi{0,1}; 16 MFMA
    if (t + 1 < 16) {
#pragma unroll
      for (int j = 0; j < 4; ++j)
        gld_lds16(srcA[j] + ko, smem + nxt + dstP[j]);
    }
    bf16x8 bwf[4][2];
#pragma unroll
    for (int ni = 0; ni < 4; ++ni)
#pragma unroll
      for (int kk = 0; kk < 2; ++kk) {
        int row = wc*64 + ni*16 + c;
        int Lb = row*128 + (kk*32 + g*8)*2;
        bwf[ni][kk] = *(const bf16x8*)(smem + (cur + 32768) + (Lb ^ ((row & 7) << 4)));
      }
    GPHASE(0)

    // ---- phase 1: stage next-B; A mi{2,3}
    __builtin_amdgcn_s_barrier();
    if (t + 1 < 16) {
#pragma unroll
      for (int j = 0; j < 4; ++j)
        gld_lds16(srcB[j] + ko, smem + nxt + 32768 + dstP[j]);
    }
    GPHASE(2)

    // ---- phase 2: A mi{4,5}
    __builtin_amdgcn_s_barrier();
    GPHASE(4)

    // ---- phase 3: A mi{6,7}
    __builtin_amdgcn_s_barrier();
    GPHASE(6)
  }
#undef GPHASE

  // epilogue: fused RoPE; C layout: col = lane&15, row = g*4 + r
#pragma unroll
  for (int mi = 0; mi < 8; ++mi) {
#pragma unroll
    for (int ni = 0; ni < 4; ++ni) {
      const int mrow0 = m0 + wr*128 + mi*16 + g*4;
      const int ncol  = n0 + wc*64 + ni*16 + c;
      const int which = ncol >> 10;          // 0=q 1=k 2=v (block-uniform)
      const int d = ncol & 1023, h = d >> 6, dd = d & 63;
      const int b = mrow0 >> 11, t0 = mrow0 & 2047;
      if (which == 2) {
        ushort4 o;
        o.x = f2bf(acc[mi][ni][0]); o.y = f2bf(acc[mi][ni][1]);
        o.z = f2bf(acc[mi][ni][2]); o.w = f2bf(acc[mi][ni][3]);
        *(ushort4*)(vt + ((size_t)((b*H_ + h)*D_ + dd))*T_ + t0) = o;
      } else {
#pragma unroll
        for (int r = 0; r < 4; ++r) {
          float val = acc[mi][ni][r];
          float partner = __shfl_xor(val, 1);          // value at dd^1 (lane^1)
          float rot = (dd & 1) ? partner : -partner;   // interleaved rotate_half
          float cv = cosT[(t0 + r)*64 + dd], sv = sinT[(t0 + r)*64 + dd];
          float o = val*cv + rot*sv;
          size_t oidx = (((size_t)(b*H_ + h))*T_ + (t0 + r))*D_ + dd;
          // q pre-scale: 1/sqrt(64) * log2(e)  (softmax done in exp2 domain)
          if (which == 0) qb[oidx] = f2bf(o * 0.180336879f);
          else            kb[oidx] = f2bf(o);
        }
      }
    }
  }
}

// ---------------------------------------------------------------- GEMM (NT, bf16), 128x128
// (unchanged proven template; used for the output projection only, EPI=1)
template<int EPI>
__global__ __launch_bounds__(256) void k_gemm(
    const unsigned short* __restrict__ A, const unsigned short* __restrict__ Bw,
    unsigned short* __restrict__ qb, unsigned short* __restrict__ kb,
    unsigned short* __restrict__ vt,
    const float* __restrict__ cosT, const float* __restrict__ sinT,
    float* __restrict__ outF)
{
  __shared__ __attribute__((aligned(16))) char smem[32768];  // A:16K B:16K
  const int tid = threadIdx.x, l = tid & 63, w = tid >> 6;
  const int g = l >> 4, c = l & 15;
  const int m0 = blockIdx.x * 128, n0 = blockIdx.y * 128;
  const int wr = w >> 1, wc = w & 1;

  const char* srcA[4]; const char* srcB[4]; int dstP[4];
#pragma unroll
  for (int j = 0; j < 4; ++j) {
    int P = w*4096 + j*1024 + l*16;
    int row = P >> 7;
    int Lb = P ^ ((row & 7) << 4);
    int col = (Lb & 127) >> 1;
    dstP[j] = P;
    srcA[j] = (const char*)A  + ((size_t)(m0 + row) * KDIM + col) * 2;
    srcB[j] = (const char*)Bw + ((size_t)(n0 + row) * KDIM + col) * 2;
  }

  f32x4 acc[4][4];
#pragma unroll
  for (int i = 0; i < 4; ++i)
#pragma unroll
    for (int j = 0; j < 4; ++j) acc[i][j] = (f32x4){0.f,0.f,0.f,0.f};

  for (int kt = 0; kt < KDIM; kt += 64) {
#pragma unroll
    for (int j = 0; j < 4; ++j) {
      gld_lds16(srcA[j] + kt*2, smem + dstP[j]);
      gld_lds16(srcB[j] + kt*2, smem + 16384 + dstP[j]);
    }
    __syncthreads();
#pragma unroll
    for (int kk = 0; kk < 2; ++kk) {
      bf16x8 af[4], bw4[4];
#pragma unroll
      for (int mi = 0; mi < 4; ++mi) {
        int row = wr*64 + mi*16 + c;
        int Lb = row*128 + (kk*32 + g*8)*2;
        af[mi] = *(const bf16x8*)(smem + (Lb ^ ((row & 7) << 4)));
      }
#pragma unroll
      for (int ni = 0; ni < 4; ++ni) {
        int row = wc*64 + ni*16 + c;
        int Lb = row*128 + (kk*32 + g*8)*2;
        bw4[ni] = *(const bf16x8*)(smem + 16384 + (Lb ^ ((row & 7) << 4)));
      }
#pragma unroll
      for (int mi = 0; mi < 4; ++mi)
#pragma unroll
        for (int ni = 0; ni < 4; ++ni)
          acc[mi][ni] = __builtin_amdgcn_mfma_f32_16x16x32_bf16(af[mi], bw4[ni], acc[mi][ni], 0, 0, 0);
    }
    __syncthreads();
  }

  // epilogue; C layout: col = lane&15, row = (lane>>4)*4 + r
#pragma unroll
  for (int mi = 0; mi < 4; ++mi) {
#pragma unroll
    for (int ni = 0; ni < 4; ++ni) {
      const int mrow0 = m0 + wr*64 + mi*16 + g*4;
      const int ncol  = n0 + wc*64 + ni*16 + c;
      if (EPI == 1) {
#pragma unroll
        for (int r = 0; r < 4; ++r)
          outF[(size_t)(mrow0 + r) * 1024 + ncol] = acc[mi][ni][r];
      } else {
        const int which = ncol >> 10;
        const int d = ncol & 1023, h = d >> 6, dd = d & 63;
        const int b = mrow0 >> 11, t0 = mrow0 & 2047;
        if (which == 2) {
          ushort4 o;
          o.x = f2bf(acc[mi][ni][0]); o.y = f2bf(acc[mi][ni][1]);
          o.z = f2bf(acc[mi][ni][2]); o.w = f2bf(acc[mi][ni][3]);
          *(ushort4*)(vt + ((size_t)((b*H_ + h)*D_ + dd))*T_ + t0) = o;
        } else {
#pragma unroll
          for (int r = 0; r < 4; ++r) {
            float val = acc[mi][ni][r];
            float partner = __shfl_xor(val, 1);
            float rot = (dd & 1) ? partner : -partner;
            float cv = cosT[(t0 + r)*64 + dd], sv = sinT[(t0 + r)*64 + dd];
            float o = val*cv + rot*sv;
            size_t oidx = (((size_t)(b*H_ + h))*T_ + (t0 + r))*D_ + dd;
            if (which == 0) qb[oidx] = f2bf(o * 0.180336879f);
            else            kb[oidx] = f2bf(o);
          }
        }
      }
    }
  }
}

// ---------------------------------------------------------------- flash attention
// (unchanged from R7 passing kernel)
__global__ __launch_bounds__(256) void k_attn(
    const unsigned short* __restrict__ qb, const unsigned short* __restrict__ kb,
    const unsigned short* __restrict__ vt, unsigned short* __restrict__ yb)
{
  __shared__ __attribute__((aligned(16))) char smem[49152]; // 2x(K:8K V:8K) + P:16K
  const int tid = threadIdx.x, l = tid & 63, w = tid >> 6;
  const int g = l >> 4, c = l & 15;
  const int bh = blockIdx.y;
  const size_t bhO = (size_t)bh * T_ * D_;
  const int pbase = 32768 + w*4096;
  const int b = bh >> 4, h = bh & 15;

  const char* srcK[2]; const char* srcV[2]; int dstP2[2];
#pragma unroll
  for (int j = 0; j < 2; ++j) {
    int P = w*2048 + j*1024 + l*16;
    int row = P >> 7;
    int Lb = P ^ ((row & 7) << 4);
    int col = (Lb & 127) >> 1;
    dstP2[j] = P;
    srcK[j] = (const char*)(kb + bhO) + ((size_t)row*D_ + col)*2;
    srcV[j] = (const char*)(vt + bhO) + ((size_t)row*T_ + col)*2;
  }

  for (int half = 0; half < 2; ++half) {
    const int qt = half ? (int)blockIdx.x : (15 - (int)blockIdx.x);
    const int q0 = qt * 128;
    const int q0w = q0 + w*32;

    bf16x8 aq[2][2];
#pragma unroll
    for (int mi = 0; mi < 2; ++mi)
#pragma unroll
      for (int kc = 0; kc < 2; ++kc) {
        int row = q0w + mi*16 + c;
        aq[mi][kc] = *(const bf16x8*)(qb + bhO + (size_t)row*D_ + kc*32 + g*8);
      }

    f32x4 po[4][2];
    float mrun[2], lrun[2];
#pragma unroll
    for (int nd = 0; nd < 4; ++nd)
#pragma unroll
      for (int mi = 0; mi < 2; ++mi) po[nd][mi] = (f32x4){0.f,0.f,0.f,0.f};
    mrun[0] = mrun[1] = -1e30f; lrun[0] = lrun[1] = 0.f;

    const int nkt = (q0 + 128) >> 6;

#pragma unroll
    for (int j = 0; j < 2; ++j) {
      gld_lds16(srcK[j], smem + dstP2[j]);
      gld_lds16(srcV[j], smem + 8192 + dstP2[j]);
    }
    __syncthreads();

    for (int it = 0; it < nkt; ++it) {
      const int kv0 = it * 64;
      const int cur = (it & 1) * 16384;
      if (it + 1 < nkt) {
        const int nxt = 16384 - cur;
        const size_t ko = (size_t)(kv0 + 64) * 128;
        const size_t vo = (size_t)(kv0 + 64) * 2;
#pragma unroll
        for (int j = 0; j < 2; ++j) {
          gld_lds16(srcK[j] + ko, smem + nxt + dstP2[j]);
          gld_lds16(srcV[j] + vo, smem + nxt + 8192 + dstP2[j]);
        }
      }

      if (kv0 < q0w + 32) {
        f32x4 st[4][2];
#pragma unroll
        for (int ni = 0; ni < 4; ++ni)
#pragma unroll
          for (int mi = 0; mi < 2; ++mi) st[ni][mi] = (f32x4){0.f,0.f,0.f,0.f};
        __builtin_amdgcn_s_setprio(1);
#pragma unroll
        for (int kk = 0; kk < 2; ++kk) {
          bf16x8 bk[4];
#pragma unroll
          for (int ni = 0; ni < 4; ++ni) {
            int kn = ni*16 + c;
            int Lb = kn*128 + (kk*32 + g*8)*2;
            bk[ni] = *(const bf16x8*)(smem + cur + (Lb ^ ((kn & 7) << 4)));
          }
#pragma unroll
          for (int ni = 0; ni < 4; ++ni)
#pragma unroll
            for (int mi = 0; mi < 2; ++mi)
              st[ni][mi] = __builtin_amdgcn_mfma_f32_16x16x32_bf16(bk[ni], aq[mi][kk], st[ni][mi], 0, 0, 0);
        }
        __builtin_amdgcn_s_setprio(0);

        if (kv0 + 64 > q0w) {
#pragma unroll
          for (int ni = 0; ni < 4; ++ni)
#pragma unroll
            for (int r = 0; r < 4; ++r) {
              int kvv = kv0 + ni*16 + g*4 + r;
#pragma unroll
              for (int mi = 0; mi < 2; ++mi) {
                int qq = q0w + mi*16 + c;
                if (kvv > qq) st[ni][mi][r] = -1e30f;
              }
            }
        }

#pragma unroll
        for (int mi = 0; mi < 2; ++mi) {
          float mt = -1e30f;
#pragma unroll
          for (int ni = 0; ni < 4; ++ni)
#pragma unroll
            for (int r = 0; r < 4; ++r) mt = fmaxf(mt, st[ni][mi][r]);
          mt = fmaxf(mt, __shfl_xor(mt, 16));
          mt = fmaxf(mt, __shfl_xor(mt, 32));
          float m_use = mrun[mi];
          if (__any(mt > m_use + 8.f)) {
            float mnew = fmaxf(m_use, mt);
            float alpha = exp2_fast(m_use - mnew);
            mrun[mi] = mnew;
            m_use = mnew;
            lrun[mi] *= alpha;
#pragma unroll
            for (int nd = 0; nd < 4; ++nd)
#pragma unroll
              for (int r = 0; r < 4; ++r) po[nd][mi][r] *= alpha;
          }
          float rs = 0.f;
#pragma unroll
          for (int ni = 0; ni < 4; ++ni)
#pragma unroll
            for (int r = 0; r < 4; ++r) {
              float p = exp2_fast(st[ni][mi][r] - m_use);
              st[ni][mi][r] = p;
              rs += p;
            }
          lrun[mi] += rs;
        }

#pragma unroll
        for (int mi = 0; mi < 2; ++mi) {
          const int row = mi*16 + c;
          const int sw = (row & 7) << 4;
          const int rb = pbase + row*128;
#pragma unroll
          for (int ni = 0; ni < 4; ++ni) {
            unsigned u0, u1;
            asm("v_cvt_pk_bf16_f32 %0, %1, %2" : "=v"(u0) : "v"(st[ni][mi][0]), "v"(st[ni][mi][1]));
            asm("v_cvt_pk_bf16_f32 %0, %1, %2" : "=v"(u1) : "v"(st[ni][mi][2]), "v"(st[ni][mi][3]));
            int Lb = (ni*16 + g*4) * 2;
            uint2 uu; uu.x = u0; uu.y = u1;
            *(uint2*)(smem + rb + (Lb ^ sw)) = uu;
          }
        }

        __builtin_amdgcn_s_setprio(1);
#pragma unroll
        for (int kk = 0; kk < 2; ++kk) {
          bf16x8 pb[2];
#pragma unroll
          for (int mi = 0; mi < 2; ++mi) {
            int pr = mi*16 + c;
            int Lb = pr*128 + (kk*32 + g*8)*2;
            pb[mi] = *(const bf16x8*)(smem + pbase + (Lb ^ ((pr & 7) << 4)));
          }
          bf16x8 bv[4];
#pragma unroll
          for (int nd = 0; nd < 4; ++nd) {
            int vr = nd*16 + c;
            int Lb = vr*128 + (kk*32 + g*8)*2;
            bv[nd] = *(const bf16x8*)(smem + cur + 8192 + (Lb ^ ((vr & 7) << 4)));
          }
#pragma unroll
          for (int nd = 0; nd < 4; ++nd)
#pragma unroll
            for (int mi = 0; mi < 2; ++mi)
              po[nd][mi] = __builtin_amdgcn_mfma_f32_16x16x32_bf16(bv[nd], pb[mi], po[nd][mi], 0, 0, 0);
        }
        __builtin_amdgcn_s_setprio(0);
      }
      __syncthreads();
    }

#pragma unroll
    for (int mi = 0; mi < 2; ++mi) {
      float ls = lrun[mi];
      ls += __shfl_xor(ls, 16);
      ls += __shfl_xor(ls, 32);
      float inv = 1.f / ls;
      int t = q0w + mi*16 + c;
#pragma unroll
      for (int nd = 0; nd < 4; ++nd) {
        ushort4 o;
        o.x = f2bf(po[nd][mi][0] * inv);
        o.y = f2bf(po[nd][mi][1] * inv);
        o.z = f2bf(po[nd][mi][2] * inv);
        o.w = f2bf(po[nd][mi][3] * inv);
        *(ushort4*)(yb + ((size_t)b*T_ + t)*C_ + h*64 + nd*16 + g*4) = o;
      }
    }
  }
}

// ---------------------------------------------------------------- launcher
extern "C" void kernel_launch(void* const* d_in, const int* in_sizes, int n_in,
                              void* d_out, int out_size, void* d_ws, size_t ws_size,
                              hipStream_t stream)
{
  const float* x  = (const float*)d_in[0];
  const float* Wq = (const float*)d_in[1];
  const float* Wk = (const float*)d_in[2];
  const float* Wv = (const float*)d_in[3];
  const float* Wp = (const float*)d_in[4];
  const int*   sp = (const int*)d_in[5];
  float* out = (float*)d_out;

  char* ws = (char*)d_ws;
  unsigned short* xb   = (unsigned short*)(ws);                  // 16 MB
  unsigned short* wcat = (unsigned short*)(ws + 16777216);       // 6 MB [Wq;Wk;Wv]
  unsigned short* wpb  = (unsigned short*)(ws + 23068672);       // 2 MB
  unsigned short* qb   = (unsigned short*)(ws + 25165824);       // 16 MB (B,H,T,D)
  unsigned short* kb   = (unsigned short*)(ws + 41943040);       // 16 MB (B,H,T,D)
  unsigned short* vt   = (unsigned short*)(ws + 58720256);       // 16 MB (B,H,D,T)
  unsigned short* yb   = (unsigned short*)(ws + 75497472);       // 16 MB (B*T, C)
  float* cosT = (float*)(ws + 92274688);                         // 512 KB [T][D]
  float* sinT = (float*)(ws + 92798976);                         // 512 KB [T][D]

  k_convert<<<dim3(2048), dim3(256), 0, stream>>>(x, Wq, Wk, Wv, Wp, xb, wcat, wpb);
  k_rope_tab<<<dim3(512), dim3(256), 0, stream>>>(sp, cosT, sinT);
  k_gemm256<<<dim3(32, 12), dim3(512), 0, stream>>>(xb, wcat, qb, kb, vt, cosT, sinT);
  k_attn<<<dim3(8, 64), dim3(256), 0, stream>>>(qb, kb, vt, yb);
  k_gemm<1><<<dim3(64, 8), dim3(256), 0, stream>>>(yb, wpb, nullptr, nullptr, nullptr, nullptr, nullptr, out);
}